// Round 4
// baseline (5089.189 us; speedup 1.0000x reference)
//
#include <hip/hip_runtime.h>
#include <cstddef>
#include <cstdint>

// Problem constants
#define LNUM 6
#define CDIM 192
#define FCH 768
#define HNUM 2
#define WREL 10
#define BNUM 8
#define TDIM 768
#define KCD 96
#define NR 21   // 2W+1

// Workspace layout (in floats).
// SHARED region (18.9MB) time-multiplexes {QKV | ATTN} (attention phase)
// and H1 (FFN phase): SZ_QKV + SZ_ACT == SZ_H1 == 8*768*768 exactly.
#define OFF_WT_QKV 0
#define SZ_WT_QKV  (6*192*576)
#define OFF_WT_O   (OFF_WT_QKV + SZ_WT_QKV)
#define SZ_WT_O    (6*192*192)
#define OFF_WT_F1  (OFF_WT_O + SZ_WT_O)
#define SZ_WT_F1   (6*576*768)
#define OFF_WT_F2  (OFF_WT_F1 + SZ_WT_F1)
#define SZ_WT_F2   (6*2304*192)
#define OFF_BIASQ  (OFF_WT_F2 + SZ_WT_F2)
#define SZ_BIASQ   (6*576)
#define OFF_SHARED (OFF_BIASQ + SZ_BIASQ)
#define SZ_QKV     (8*576*768)
#define SZ_ACT     (8*192*768)
#define SZ_SHARED  (8*768*768)
#define OFF_Y      (OFF_SHARED + SZ_SHARED)
#define OFF_XCUR   (OFF_Y + SZ_ACT)
// total = OFF_XCUR + SZ_ACT = 13,274,496 floats = 53.1 MB

// ---------------------------------------------------------------------------
// Prep: transpose all weights to [cin*k][cout] layout, stack qkv biases.
// jobs: 0=wq 1=wk 2=wv 3=wo 4=wf1 5=wf2 6=bias
// ---------------------------------------------------------------------------
__global__ __launch_bounds__(256) void prep_kernel(
    const float* __restrict__ wq, const float* __restrict__ wk,
    const float* __restrict__ wv, const float* __restrict__ wo,
    const float* __restrict__ wf1, const float* __restrict__ wf2,
    const float* __restrict__ bq, const float* __restrict__ bk,
    const float* __restrict__ bv, float* __restrict__ ws)
{
    int l = blockIdx.z;
    int job = blockIdx.y;
    int bx = blockIdx.x;

    if (job == 6) {
        if (bx == 0) {
            float* dst = ws + OFF_BIASQ + l * 576;
            for (int j = threadIdx.x; j < 576; j += 256) {
                float v;
                if (j < 192)      v = bq[l * 192 + j];
                else if (j < 384) v = bk[l * 192 + j - 192];
                else              v = bv[l * 192 + j - 384];
                dst[j] = v;
            }
        }
        return;
    }

    const float* src = nullptr; float* dst = nullptr;
    int R = 0, S = 0, ldd = 0, coff = 0;
    switch (job) {
        case 0: src = wq + (size_t)l*36864;  R=192; S=192;  dst = ws + OFF_WT_QKV + (size_t)l*110592; ldd=576; coff=0;   break;
        case 1: src = wk + (size_t)l*36864;  R=192; S=192;  dst = ws + OFF_WT_QKV + (size_t)l*110592; ldd=576; coff=192; break;
        case 2: src = wv + (size_t)l*36864;  R=192; S=192;  dst = ws + OFF_WT_QKV + (size_t)l*110592; ldd=576; coff=384; break;
        case 3: src = wo + (size_t)l*36864;  R=192; S=192;  dst = ws + OFF_WT_O   + (size_t)l*36864;  ldd=192; coff=0;   break;
        case 4: src = wf1 + (size_t)l*442368; R=768; S=576; dst = ws + OFF_WT_F1  + (size_t)l*442368; ldd=768; coff=0;   break;
        case 5: src = wf2 + (size_t)l*442368; R=192; S=2304;dst = ws + OFF_WT_F2  + (size_t)l*442368; ldd=192; coff=0;   break;
        default: return;
    }
    int nrt = (R + 31) / 32;
    int rt = bx % nrt, st = bx / nrt;
    if (st * 32 >= S) return;

    __shared__ float tile[32][33];
    int r0 = rt * 32, s0 = st * 32;
    int tl = threadIdx.x & 31, tg = threadIdx.x >> 5;
    for (int rr = tg; rr < 32; rr += 8) {
        int r = r0 + rr, s = s0 + tl;
        tile[rr][tl] = (r < R && s < S) ? src[(size_t)r * S + s] : 0.f;
    }
    __syncthreads();
    for (int rr = tg; rr < 32; rr += 8) {
        int s = s0 + rr, r = r0 + tl;
        if (s < S && r < R)
            dst[(size_t)s * ldd + coff + r] = tile[tl][rr];
    }
}

// ---------------------------------------------------------------------------
// Fused GEMM / conv1d kernel.
// Wt: [Cin*KW][M] (pre-transposed), X: [B][Cin][T], Y: [B][M][T]
// 64x64 tile, 4x4 register blocking, 16-channel LDS chunks.
// ---------------------------------------------------------------------------
template<int KW, bool MASKIN, bool RELU, bool QKV, bool OUTMASK>
__global__ __launch_bounds__(256) void gemm_conv(
    const float* __restrict__ Wt, const float* __restrict__ Xg,
    const float* __restrict__ bias, const float* __restrict__ mask,
    float* __restrict__ Y, int M, int Cin)
{
    constexpr int TN = 64, TM = 64, CC = 16;
    constexpr int XW = TN + KW - 1;          // 64 or 66
    constexpr int XP = (KW == 1) ? 64 : 68;  // padded (16B-aligned rows)
    __shared__ float xs[CC][XP];
    __shared__ float wsm[CC * KW][TM];

    int b  = blockIdx.z;
    int t0 = blockIdx.x * TN;
    int m0 = blockIdx.y * TM;
    int tid = threadIdx.x;
    int tx = tid & 15;   // t group (16 x 4)
    int ty = tid >> 4;   // m group (16 x 4)

    const float* Xb = Xg + (size_t)b * Cin * TDIM;
    const float* mb = mask + (size_t)b * TDIM;

    float acc[4][4] = {};

    for (int c0 = 0; c0 < Cin; c0 += CC) {
        __syncthreads();
        for (int idx = tid; idx < CC * XW; idx += 256) {
            int c = idx / XW, j = idx - c * XW;
            int tg = t0 + j - (KW / 2);
            float v = 0.f;
            if (tg >= 0 && tg < TDIM) {
                v = Xb[(size_t)(c0 + c) * TDIM + tg];
                if (MASKIN) v *= mb[tg];
            }
            xs[c][j] = v;
        }
        for (int idx = tid; idx < CC * KW * TM; idx += 256) {
            int r = idx >> 6, m = idx & 63;
            wsm[r][m] = Wt[(size_t)(c0 * KW + r) * M + m0 + m];
        }
        __syncthreads();
        #pragma unroll
        for (int c = 0; c < CC; ++c) {
            float xv[KW + 3];
            float4 x4 = *(const float4*)&xs[c][tx * 4];
            xv[0] = x4.x; xv[1] = x4.y; xv[2] = x4.z; xv[3] = x4.w;
            if constexpr (KW == 3) {
                xv[4] = xs[c][tx * 4 + 4];
                xv[5] = xs[c][tx * 4 + 5];
            }
            #pragma unroll
            for (int k = 0; k < KW; ++k) {
                float4 w4 = *(const float4*)&wsm[c * KW + k][ty * 4];
                float wv[4] = {w4.x, w4.y, w4.z, w4.w};
                #pragma unroll
                for (int i = 0; i < 4; ++i)
                    #pragma unroll
                    for (int j = 0; j < 4; ++j)
                        acc[i][j] += wv[i] * xv[j + k];
            }
        }
    }

    const float qscale = 0.10206207261596575f; // 1/sqrt(96)
    #pragma unroll
    for (int i = 0; i < 4; ++i) {
        int m = m0 + ty * 4 + i;
        float bv = bias[m];
        float4 o;
        float vals[4];
        #pragma unroll
        for (int j = 0; j < 4; ++j) {
            float v = acc[i][j] + bv;
            if constexpr (QKV) { if (m < 192) v *= qscale; }
            if constexpr (RELU) v = fmaxf(v, 0.f);
            if constexpr (OUTMASK) v *= mb[t0 + tx * 4 + j];
            vals[j] = v;
        }
        o.x = vals[0]; o.y = vals[1]; o.z = vals[2]; o.w = vals[3];
        *(float4*)&Y[((size_t)b * M + m) * TDIM + t0 + tx * 4] = o;
    }
}

// ---------------------------------------------------------------------------
// Flash attention v2.1: register-q, shuffle-reduced scores, register softmax
// stats, structured rel-v buckets (band + two clipped accumulators).
// Block: 64 rows (t), 256 threads = 32 row-pairs x 8 dim-lanes (12 dims each).
// qkv: [B][576][T] (q pre-scaled by 1/sqrt(96)), out: [B][192][T]
// ---------------------------------------------------------------------------
__global__ __launch_bounds__(256) void attn_kernel(
    const float* __restrict__ qkv, const float* __restrict__ erk,
    const float* __restrict__ erv, float* __restrict__ out)
{
    int b = blockIdx.z, h = blockIdx.y;
    int t0 = blockIdx.x * 64;
    int tid = threadIdx.x;
    int r2 = tid >> 3;          // row-pair 0..31
    int j  = tid & 7;           // dim-lane 0..7
    int lr0 = 2 * r2, lr1 = lr0 + 1;
    int row0 = t0 + lr0, row1 = t0 + lr1;
    int d0 = 12 * j;

    __shared__ float smem[6400];      // qs[64][100]  |  { ks[32][100], vs[32][100] }
    __shared__ float erks[NR * 100];  // erk staged [21][100] (separate buffer)
    __shared__ float lg[64][21];      // rel-key logits per row
    __shared__ float band[64][20];    // interior rel-v buckets (19 used)

    float* qs = smem;                 // [64][100]
    float* ks = smem;                 // [32][100]
    float* vs = smem + 3200;          // [32][100]

    const float* qb = qkv + ((size_t)b * 576 + h * 96) * TDIM;
    const float* kb = qkv + ((size_t)b * 576 + 192 + h * 96) * TDIM;
    const float* vb = qkv + ((size_t)b * 576 + 384 + h * 96) * TDIM;

    // stage q tile [64][96] (coalesced), erk into its own buffer
    for (int idx = tid; idx < 64 * 96; idx += 256) {
        int t = idx & 63, d = idx >> 6;
        qs[t * 100 + d] = qb[(size_t)d * TDIM + t0 + t];
    }
    for (int idx = tid; idx < 21 * 96; idx += 256) {
        int r = idx / 96, d = idx - r * 96;
        erks[r * 100 + d] = erk[r * 96 + d];
    }
    for (int idx = tid; idx < 64 * 20; idx += 256)
        (&band[0][0])[idx] = 0.f;
    __syncthreads();

    // q fragments into registers
    float q0[12], q1[12];
    #pragma unroll
    for (int c = 0; c < 3; ++c) {
        float4 a  = *(const float4*)&qs[lr0 * 100 + d0 + 4 * c];
        float4 b4 = *(const float4*)&qs[lr1 * 100 + d0 + 4 * c];
        q0[4*c+0]=a.x;  q0[4*c+1]=a.y;  q0[4*c+2]=a.z;  q0[4*c+3]=a.w;
        q1[4*c+0]=b4.x; q1[4*c+1]=b4.y; q1[4*c+2]=b4.z; q1[4*c+3]=b4.w;
    }

    // rel-key logits: dot over own 12 dims + 8-lane butterfly
    for (int r = 0; r < NR; ++r) {
        float pa = 0.f, pb = 0.f;
        #pragma unroll
        for (int c = 0; c < 3; ++c) {
            float4 kv = *(const float4*)&erks[r * 100 + d0 + 4 * c];
            pa += q0[4*c+0]*kv.x + q0[4*c+1]*kv.y + q0[4*c+2]*kv.z + q0[4*c+3]*kv.w;
            pb += q1[4*c+0]*kv.x + q1[4*c+1]*kv.y + q1[4*c+2]*kv.z + q1[4*c+3]*kv.w;
        }
        pa += __shfl_xor(pa, 1); pa += __shfl_xor(pa, 2); pa += __shfl_xor(pa, 4);
        pb += __shfl_xor(pb, 1); pb += __shfl_xor(pb, 2); pb += __shfl_xor(pb, 4);
        if (j == 0) { lg[lr0][r] = pa; lg[lr1][r] = pb; }
    }

    float p0[32], p1[32];
    float acc0[12] = {}, acc1[12] = {};
    float m0 = -1e30f, m1 = -1e30f, l0 = 0.f, l1 = 0.f;
    float A0 = 0.f, B0 = 0.f, A1 = 0.f, B1 = 0.f;

    for (int s0 = 0; s0 < TDIM; s0 += 32) {
        __syncthreads();   // protects qs (first iter) and ks/vs (later iters)
        for (int idx = tid; idx < 3072; idx += 256) {
            int s = idx & 31, d = idx >> 5;
            ks[s * 100 + d] = kb[(size_t)d * TDIM + s0 + s];
            vs[s * 100 + d] = vb[(size_t)d * TDIM + s0 + s];
        }
        __syncthreads();

        // scores: dot over own 12 dims + 8-lane butterfly (serves both rows)
        #pragma unroll
        for (int s = 0; s < 32; ++s) {
            float pa = 0.f, pb = 0.f;
            #pragma unroll
            for (int c = 0; c < 3; ++c) {
                float4 kv = *(const float4*)&ks[s * 100 + d0 + 4 * c];
                pa += q0[4*c+0]*kv.x + q0[4*c+1]*kv.y + q0[4*c+2]*kv.z + q0[4*c+3]*kv.w;
                pb += q1[4*c+0]*kv.x + q1[4*c+1]*kv.y + q1[4*c+2]*kv.z + q1[4*c+3]*kv.w;
            }
            pa += __shfl_xor(pa, 1); pa += __shfl_xor(pa, 2); pa += __shfl_xor(pa, 4);
            pb += __shfl_xor(pb, 1); pb += __shfl_xor(pb, 2); pb += __shfl_xor(pb, 4);
            p0[s] = pa; p1[s] = pb;
        }

        // bias + running max
        float nm0 = m0, nm1 = m1;
        #pragma unroll
        for (int s = 0; s < 32; ++s) {
            int rel0 = min(max(row0 - (s0 + s) + WREL, 0), 2 * WREL);
            int rel1 = min(max(row1 - (s0 + s) + WREL, 0), 2 * WREL);
            p0[s] += lg[lr0][rel0];
            p1[s] += lg[lr1][rel1];
            nm0 = fmaxf(nm0, p0[s]); nm1 = fmaxf(nm1, p1[s]);
        }
        float rs0 = __expf(m0 - nm0), rs1 = __expf(m1 - nm1);
        m0 = nm0; m1 = nm1;
        // rescale OLD state; skip entirely when max didn't move (common case).
        // wave-lockstep orders these DS ops before the band stores below.
        if (rs0 != 1.f || rs1 != 1.f) {
            for (int bb = j; bb < 19; bb += 8) {
                band[lr0][bb] *= rs0;
                band[lr1][bb] *= rs1;
            }
            l0 *= rs0; A0 *= rs0; B0 *= rs0;
            l1 *= rs1; A1 *= rs1; B1 *= rs1;
            #pragma unroll
            for (int jj = 0; jj < 12; ++jj) { acc0[jj] *= rs0; acc1[jj] *= rs1; }
        }

        // exp + l + rel-v buckets (interior buckets hit exactly once globally)
        #pragma unroll
        for (int s = 0; s < 32; ++s) {
            float e0 = __expf(p0[s] - nm0);
            float e1 = __expf(p1[s] - nm1);
            p0[s] = e0; p1[s] = e1;
            l0 += e0; l1 += e1;
            int g0 = row0 - (s0 + s) + WREL;
            int g1 = row1 - (s0 + s) + WREL;
            if (g0 <= 0) A0 += e0; else if (g0 >= 2 * WREL) B0 += e0;
            else if (j == 0) band[lr0][g0 - 1] = e0;
            if (g1 <= 0) A1 += e1; else if (g1 >= 2 * WREL) B1 += e1;
            else if (j == 0) band[lr1][g1 - 1] = e1;
        }

        // p @ v
        #pragma unroll
        for (int s = 0; s < 32; ++s) {
            float e0 = p0[s], e1 = p1[s];
            #pragma unroll
            for (int c = 0; c < 3; ++c) {
                float4 vv = *(const float4*)&vs[s * 100 + d0 + 4 * c];
                acc0[4*c+0] += e0 * vv.x; acc0[4*c+1] += e0 * vv.y;
                acc0[4*c+2] += e0 * vv.z; acc0[4*c+3] += e0 * vv.w;
                acc1[4*c+0] += e1 * vv.x; acc1[4*c+1] += e1 * vv.y;
                acc1[4*c+2] += e1 * vv.z; acc1[4*c+3] += e1 * vv.w;
            }
        }
    }

    // epilogue: add rel-v contribution, normalize, store
    float o0[12], o1[12];
    #pragma unroll
    for (int jj = 0; jj < 12; ++jj) {
        float ev0  = erv[0 * 96 + d0 + jj];
        float ev20 = erv[2 * WREL * 96 + d0 + jj];
        o0[jj] = acc0[jj] + A0 * ev0 + B0 * ev20;
        o1[jj] = acc1[jj] + A1 * ev0 + B1 * ev20;
    }
    for (int rel = 1; rel <= 19; ++rel) {
        float b0v = band[lr0][rel - 1];
        float b1v = band[lr1][rel - 1];
        #pragma unroll
        for (int jj = 0; jj < 12; ++jj) {
            float ev = erv[rel * 96 + d0 + jj];
            o0[jj] += b0v * ev;
            o1[jj] += b1v * ev;
        }
    }
    float inv0 = 1.0f / l0, inv1 = 1.0f / l1;
    float* ob = out + ((size_t)b * CDIM + h * 96) * TDIM;
    #pragma unroll
    for (int jj = 0; jj < 12; ++jj) {
        ob[(size_t)(d0 + jj) * TDIM + row0] = o0[jj] * inv0;
        ob[(size_t)(d0 + jj) * TDIM + row1] = o1[jj] * inv1;
    }
}

// ---------------------------------------------------------------------------
// Residual + channel LayerNorm. out = gamma*norm(xres+y)+beta (optionally *mask)
// ---------------------------------------------------------------------------
__global__ __launch_bounds__(256) void ln_kernel(
    const float* __restrict__ xres, const float* __restrict__ y,
    const float* __restrict__ gamma, const float* __restrict__ beta,
    const float* __restrict__ mask, float* __restrict__ outp, int applymask)
{
    int b = blockIdx.y;
    int tl = threadIdx.x & 31;
    int g  = threadIdx.x >> 5;
    int t  = blockIdx.x * 32 + tl;

    __shared__ float part[2][8][32];

    const float* xb = xres + (size_t)b * CDIM * TDIM + t;
    const float* yb = y    + (size_t)b * CDIM * TDIM + t;

    float s = 0.f, ss = 0.f;
    for (int c = g * 24; c < g * 24 + 24; ++c) {
        float v = xb[(size_t)c * TDIM] + yb[(size_t)c * TDIM];
        s += v; ss += v * v;
    }
    part[0][g][tl] = s;
    part[1][g][tl] = ss;
    __syncthreads();
    float S = 0.f, SS = 0.f;
    #pragma unroll
    for (int gg = 0; gg < 8; ++gg) { S += part[0][gg][tl]; SS += part[1][gg][tl]; }
    float mean = S * (1.0f / 192.0f);
    float var  = SS * (1.0f / 192.0f) - mean * mean;
    float rstd = rsqrtf(var + 1e-5f);
    float mk = applymask ? mask[(size_t)b * TDIM + t] : 1.f;

    float* ob = outp + (size_t)b * CDIM * TDIM + t;
    for (int c = g * 24; c < g * 24 + 24; ++c) {
        float v = xb[(size_t)c * TDIM] + yb[(size_t)c * TDIM];
        float r = gamma[c] * ((v - mean) * rstd) + beta[c];
        if (applymask) r *= mk;
        ob[(size_t)c * TDIM] = r;
    }
}

// ---------------------------------------------------------------------------
extern "C" void kernel_launch(void* const* d_in, const int* in_sizes, int n_in,
                              void* d_out, int out_size, void* d_ws, size_t ws_size,
                              hipStream_t stream)
{
    const float* x_in  = (const float*)d_in[0];
    const float* mask  = (const float*)d_in[1];
    const float* w_q   = (const float*)d_in[2];
    const float* b_q   = (const float*)d_in[3];
    const float* w_k   = (const float*)d_in[4];
    const float* b_k   = (const float*)d_in[5];
    const float* w_v   = (const float*)d_in[6];
    const float* b_v   = (const float*)d_in[7];
    const float* w_o   = (const float*)d_in[8];
    const float* b_o   = (const float*)d_in[9];
    const float* erk   = (const float*)d_in[10];
    const float* erv   = (const float*)d_in[11];
    const float* g1    = (const float*)d_in[12];
    const float* be1   = (const float*)d_in[13];
    const float* w_f1  = (const float*)d_in[14];
    const float* b_f1  = (const float*)d_in[15];
    const float* w_f2  = (const float*)d_in[16];
    const float* b_f2  = (const float*)d_in[17];
    const float* g2    = (const float*)d_in[18];
    const float* be2   = (const float*)d_in[19];

    float* ws  = (float*)d_ws;
    float* out = (float*)d_out;

    float* WTQKV = ws + OFF_WT_QKV;
    float* WTO   = ws + OFF_WT_O;
    float* WTF1  = ws + OFF_WT_F1;
    float* WTF2  = ws + OFF_WT_F2;
    float* BQKV  = ws + OFF_BIASQ;
    // SHARED region: {QKV | ATTN} during attention phase, H1 during FFN phase
    float* QKVB  = ws + OFF_SHARED;
    float* ATTN  = ws + OFF_SHARED + SZ_QKV;
    float* H1    = ws + OFF_SHARED;
    float* YB    = ws + OFF_Y;
    float* XCUR  = ws + OFF_XCUR;

    prep_kernel<<<dim3(432, 7, 6), 256, 0, stream>>>(w_q, w_k, w_v, w_o, w_f1, w_f2,
                                                     b_q, b_k, b_v, ws);

    for (int l = 0; l < LNUM; ++l) {
        const float* xc = (l == 0) ? x_in : XCUR;

        // QKV projection (q pre-scaled), input masked
        gemm_conv<1, true, false, true, false><<<dim3(12, 9, 8), 256, 0, stream>>>(
            WTQKV + (size_t)l * 110592, xc, BQKV + l * 576, mask, QKVB, 576, 192);

        attn_kernel<<<dim3(12, 2, 8), 256, 0, stream>>>(
            QKVB, erk + (size_t)l * NR * KCD, erv + (size_t)l * NR * KCD, ATTN);

        // output projection
        gemm_conv<1, false, false, false, false><<<dim3(12, 3, 8), 256, 0, stream>>>(
            WTO + (size_t)l * 36864, ATTN, b_o + l * 192, mask, YB, 192, 192);

        // x = LN(x + y)
        ln_kernel<<<dim3(24, 8), 256, 0, stream>>>(xc, YB, g1 + l * 192, be1 + l * 192,
                                                   mask, XCUR, 0);

        // FFN conv1 (K=3) + ReLU, input masked  (H1 overwrites QKV/ATTN - both dead)
        gemm_conv<3, true, true, false, false><<<dim3(12, 12, 8), 256, 0, stream>>>(
            WTF1 + (size_t)l * 442368, XCUR, b_f1 + l * FCH, mask, H1, 768, 192);

        // FFN conv2 (K=3), input masked, output masked
        gemm_conv<3, true, false, false, true><<<dim3(12, 3, 8), 256, 0, stream>>>(
            WTF2 + (size_t)l * 442368, H1, b_f2 + l * 192, mask, YB, 192, 768);

        bool last = (l == LNUM - 1);
        ln_kernel<<<dim3(24, 8), 256, 0, stream>>>(XCUR, YB, g2 + l * 192, be2 + l * 192,
                                                   mask, last ? out : XCUR, last ? 1 : 0);
    }
}

// Round 6
// 2894.855 us; speedup vs baseline: 1.7580x; 1.7580x over previous
//
#include <hip/hip_runtime.h>
#include <cstddef>
#include <cstdint>

// Problem constants
#define LNUM 6
#define CDIM 192
#define FCH 768
#define HNUM 2
#define WREL 10
#define BNUM 8
#define TDIM 768
#define KCD 96
#define NR 21   // 2W+1

typedef short s16x8 __attribute__((ext_vector_type(8)));
typedef float f32x4 __attribute__((ext_vector_type(4)));

__device__ __forceinline__ unsigned short f2bf(float f) {
    unsigned u = __builtin_bit_cast(unsigned, f);
    u += 0x7FFF + ((u >> 16) & 1);          // round-to-nearest-even
    return (unsigned short)(u >> 16);
}

// ---------------------------------------------------------------------------
// Workspace layout (BYTE offsets). Weights bf16 (ushort), activations fp32.
// ---------------------------------------------------------------------------
#define OFFB_WQKV   ((size_t)0)
#define SZB_WQKV    ((size_t)LNUM*576*192*2)
#define OFFB_WO     (OFFB_WQKV + SZB_WQKV)
#define SZB_WO      ((size_t)LNUM*192*192*2)
#define OFFB_WF1    (OFFB_WO + SZB_WO)
#define SZB_WF1     ((size_t)LNUM*3*768*192*2)
#define OFFB_WF2    (OFFB_WF1 + SZB_WF1)
#define SZB_WF2     ((size_t)LNUM*3*192*768*2)
#define OFFB_BQKV   (OFFB_WF2 + SZB_WF2)
#define SZB_BQKV    ((size_t)LNUM*576*4)
#define OFFB_SHARED (OFFB_BQKV + SZB_BQKV)
#define SZB_QKV     ((size_t)BNUM*576*TDIM*4)
#define SZB_ACT     ((size_t)BNUM*CDIM*TDIM*4)
#define SZB_SHARED  ((size_t)BNUM*768*TDIM*4)   // {QKV|ATTN} == H1, time-multiplexed
#define OFFB_Y      (OFFB_SHARED + SZB_SHARED)
#define OFFB_XCUR   (OFFB_Y + SZB_ACT)
// total ~40.7 MB (53.1 MB worked in the R4 bench)

// ---------------------------------------------------------------------------
// Prep: weights -> bf16 [KW][M][Cin] per layer; qkv bias stacked (q scaled).
// blockIdx.y = job: 0=QKV 1=O 2=F1 3=F2 4=bias
// ---------------------------------------------------------------------------
__global__ __launch_bounds__(256) void prep_kernel(
    const float* __restrict__ wq, const float* __restrict__ wk,
    const float* __restrict__ wv, const float* __restrict__ wo,
    const float* __restrict__ wf1, const float* __restrict__ wf2,
    const float* __restrict__ bq, const float* __restrict__ bk,
    const float* __restrict__ bv, char* __restrict__ wsb)
{
    const float qscale = 0.10206207261596575f; // 1/sqrt(96)
    int job = blockIdx.y;
    int stride = gridDim.x * 256;
    int base = blockIdx.x * 256 + threadIdx.x;

    if (job == 0) {
        unsigned short* dst = (unsigned short*)(wsb + OFFB_WQKV);
        const int N = LNUM * 576 * 192;
        for (int idx = base; idx < N; idx += stride) {
            int c = idx % 192;
            int m = (idx / 192) % 576;
            int l = idx / (192 * 576);
            float v;
            if (m < 192)      v = wq[((size_t)l*192 + m)*192 + c] * qscale;
            else if (m < 384) v = wk[((size_t)l*192 + (m-192))*192 + c];
            else              v = wv[((size_t)l*192 + (m-384))*192 + c];
            dst[idx] = f2bf(v);
        }
    } else if (job == 1) {
        unsigned short* dst = (unsigned short*)(wsb + OFFB_WO);
        const int N = LNUM * 192 * 192;
        for (int idx = base; idx < N; idx += stride)
            dst[idx] = f2bf(wo[idx]);       // already [l][m][c]
    } else if (job == 2) {
        unsigned short* dst = (unsigned short*)(wsb + OFFB_WF1);
        const int N = LNUM * 3 * 768 * 192;
        for (int idx = base; idx < N; idx += stride) {
            int c = idx % 192;
            int m = (idx / 192) % 768;
            int k = (idx / (192*768)) % 3;
            int l = idx / (192*768*3);
            dst[idx] = f2bf(wf1[(((size_t)l*768 + m)*192 + c)*3 + k]);
        }
    } else if (job == 3) {
        unsigned short* dst = (unsigned short*)(wsb + OFFB_WF2);
        const int N = LNUM * 3 * 192 * 768;
        for (int idx = base; idx < N; idx += stride) {
            int c = idx % 768;
            int m = (idx / 768) % 192;
            int k = (idx / (768*192)) % 3;
            int l = idx / (768*192*3);
            dst[idx] = f2bf(wf2[(((size_t)l*192 + m)*768 + c)*3 + k]);
        }
    } else {
        float* dst = (float*)(wsb + OFFB_BQKV);
        const int N = LNUM * 576;
        for (int idx = base; idx < N; idx += stride) {
            int j = idx % 576, l = idx / 576;
            float v;
            if (j < 192)      v = bq[l*192 + j] * qscale;
            else if (j < 384) v = bk[l*192 + j - 192];
            else              v = bv[l*192 + j - 384];
            dst[idx] = v;
        }
    }
}

// ---------------------------------------------------------------------------
// bf16 MFMA GEMM / conv1d.  Wb: bf16 [KW][M][Cin], X: f32 [B][Cin][T],
// Y: f32 [B][M][T].  64(t)x64(m) tile, 4 waves (2x2), K-chunk 64,
// mfma_f32_16x16x32_bf16.  A: row=lane&15 (t), k=(lane>>4)*8+e (c);
// B: col=lane&15 (m), same k.  C/D: col=lane&15 (m), row=(lane>>4)*4+reg (t)
// [verified: learn_hip m89/m91].  Epilogue transposes through LDS for
// coalesced stores.
// ---------------------------------------------------------------------------
template<int KW, bool MASKIN, bool RELU, bool OUTMASK>
__global__ __launch_bounds__(256) void gemm_mfma(
    const unsigned short* __restrict__ Wb, const float* __restrict__ Xg,
    const float* __restrict__ bias, const float* __restrict__ mask,
    float* __restrict__ Y, int M, int Cin)
{
    constexpr int H = KW / 2;
    constexpr int ROWS = 64 + 2 * H;     // 64 or 66
    constexpr int CC = 64;               // K-chunk (channels)
    constexpr int CP = 72;               // padded row (bf16), 144B: b128-aligned
    constexpr int SMEM_BYTES = (ROWS + KW * 64) * CP * 2;  // >= 64*65*4 both KW
    __shared__ __align__(16) char smem_raw[SMEM_BYTES];
    unsigned short (*xs)[CP] = (unsigned short(*)[CP])smem_raw;
    unsigned short (*wsm)[64][CP] = (unsigned short(*)[64][CP])(smem_raw + ROWS * CP * 2);

    int b  = blockIdx.z;
    int t0 = blockIdx.x * 64;
    int m0 = blockIdx.y * 64;
    int tid  = threadIdx.x;
    int wave = tid >> 6, lane = tid & 63;
    int wr = wave >> 1, wc = wave & 1;
    int lrow = lane & 15, lkg = lane >> 4;

    const float* Xb = Xg + (size_t)b * Cin * TDIM;
    const float* mb = mask + (size_t)b * TDIM;

    f32x4 acc[2][2];
    #pragma unroll
    for (int i = 0; i < 2; ++i)
        #pragma unroll
        for (int j = 0; j < 2; ++j)
            acc[i][j] = f32x4{0.f, 0.f, 0.f, 0.f};

    for (int c0 = 0; c0 < Cin; c0 += CC) {
        __syncthreads();
        // stage X chunk (f32 -> bf16), t-fastest global reads (coalesced)
        for (int idx = tid; idx < ROWS * CC; idx += 256) {
            int c = idx / ROWS;
            int tt = idx - c * ROWS;
            int tg = t0 + tt - H;
            float v = 0.f;
            if (tg >= 0 && tg < TDIM) {
                v = Xb[(size_t)(c0 + c) * TDIM + tg];
                if (MASKIN) v *= mb[tg];
            }
            xs[tt][c] = f2bf(v);
        }
        // stage W chunk (8B vector copies, coalesced)
        const unsigned short* Wc = Wb + c0;
        for (int idx = tid; idx < KW * 64 * (CC / 4); idx += 256) {
            int k = idx / (64 * (CC / 4));
            int rem = idx - k * 64 * (CC / 4);
            int m = rem >> 4;
            int c4 = rem & 15;
            *(uint2*)&wsm[k][m][c4 * 4] =
                *(const uint2*)(Wc + ((size_t)k * M + m0 + m) * Cin + c4 * 4);
        }
        __syncthreads();

        #pragma unroll
        for (int k = 0; k < KW; ++k) {
            #pragma unroll
            for (int ks = 0; ks < CC / 32; ++ks) {
                s16x8 a0 = *(const s16x8*)&xs[32*wr +  0 + lrow + k][ks*32 + lkg*8];
                s16x8 a1 = *(const s16x8*)&xs[32*wr + 16 + lrow + k][ks*32 + lkg*8];
                s16x8 b0 = *(const s16x8*)&wsm[k][32*wc +  0 + lrow][ks*32 + lkg*8];
                s16x8 b1 = *(const s16x8*)&wsm[k][32*wc + 16 + lrow][ks*32 + lkg*8];
                acc[0][0] = __builtin_amdgcn_mfma_f32_16x16x32_bf16(a0, b0, acc[0][0], 0, 0, 0);
                acc[0][1] = __builtin_amdgcn_mfma_f32_16x16x32_bf16(a0, b1, acc[0][1], 0, 0, 0);
                acc[1][0] = __builtin_amdgcn_mfma_f32_16x16x32_bf16(a1, b0, acc[1][0], 0, 0, 0);
                acc[1][1] = __builtin_amdgcn_mfma_f32_16x16x32_bf16(a1, b1, acc[1][1], 0, 0, 0);
            }
        }
    }

    // epilogue: bias/relu/mask in regs, transpose via LDS, coalesced stores
    __syncthreads();                       // staging reads done block-wide
    float* tile = (float*)smem_raw;        // [64][65] f32
    #pragma unroll
    for (int i = 0; i < 2; ++i) {
        #pragma unroll
        for (int j = 0; j < 2; ++j) {
            int ml = 32 * wc + 16 * j + lrow;
            float bv = bias[m0 + ml];
            #pragma unroll
            for (int r = 0; r < 4; ++r) {
                int tl = 32 * wr + 16 * i + lkg * 4 + r;
                float v = acc[i][j][r] + bv;
                if (RELU) v = fmaxf(v, 0.f);
                if (OUTMASK) v *= mb[t0 + tl];
                tile[tl * 65 + ml] = v;
            }
        }
    }
    __syncthreads();
    for (int idx = tid; idx < 64 * 16; idx += 256) {
        int m = idx >> 4, tq = (idx & 15) * 4;
        float4 o;
        o.x = tile[(tq + 0) * 65 + m];
        o.y = tile[(tq + 1) * 65 + m];
        o.z = tile[(tq + 2) * 65 + m];
        o.w = tile[(tq + 3) * 65 + m];
        *(float4*)&Y[((size_t)b * M + m0 + m) * TDIM + t0 + tq] = o;
    }
}

// ---------------------------------------------------------------------------
// Flash attention v4: 16-row tiles, 128 threads = 16 rows x 8 dim-lanes
// (1 row per group).  Grid 768 blocks -> 3 blocks/CU.  Register q, shuffle
// scores, register softmax stats, structured rel-v buckets, LDS-transposed
// output store.  qkv: [B][576][T] (q pre-scaled), out: [B][192][T]
// ---------------------------------------------------------------------------
__global__ __launch_bounds__(128) void attn_kernel(
    const float* __restrict__ qkv, const float* __restrict__ erk,
    const float* __restrict__ erv, float* __restrict__ out)
{
    constexpr int STR = 100;
    int b = blockIdx.z, h = blockIdx.y;
    int t0 = blockIdx.x * 16;
    int tid = threadIdx.x;
    int r = tid >> 3;            // 0..15 (row within tile)
    int j = tid & 7;             // dim-lane
    int row = t0 + r;
    int d0 = 12 * j;

    __shared__ float smem[2 * 32 * STR];   // ks|vs; qs aliases ks; osm aliases
    __shared__ float erks[NR * STR];
    __shared__ float lg[16][NR];
    __shared__ float band[16][20];

    float* qs = smem;
    float* ks = smem;
    float* vs = smem + 32 * STR;

    const float* qb = qkv + ((size_t)b * 576 + h * 96) * TDIM;
    const float* kb = qb + (size_t)192 * TDIM;
    const float* vb = qb + (size_t)384 * TDIM;

    for (int idx = tid; idx < 16 * 96; idx += 128) {
        int t = idx & 15, d = idx >> 4;
        qs[t * STR + d] = qb[(size_t)d * TDIM + t0 + t];
    }
    for (int idx = tid; idx < NR * 96; idx += 128) {
        int rr = idx / 96, d = idx - rr * 96;
        erks[rr * STR + d] = erk[rr * 96 + d];
    }
    for (int idx = tid; idx < 16 * 20; idx += 128)
        (&band[0][0])[idx] = 0.f;
    __syncthreads();

    float q[12];
    #pragma unroll
    for (int c = 0; c < 3; ++c) {
        float4 a = *(const float4*)&qs[r * STR + d0 + 4 * c];
        q[4*c+0] = a.x; q[4*c+1] = a.y; q[4*c+2] = a.z; q[4*c+3] = a.w;
    }

    // rel-key logits (dot over own 12 dims + 3-step butterfly)
    for (int rr = 0; rr < NR; ++rr) {
        float pa = 0.f;
        #pragma unroll
        for (int c = 0; c < 3; ++c) {
            float4 kv = *(const float4*)&erks[rr * STR + d0 + 4 * c];
            pa += q[4*c]*kv.x + q[4*c+1]*kv.y + q[4*c+2]*kv.z + q[4*c+3]*kv.w;
        }
        pa += __shfl_xor(pa, 1); pa += __shfl_xor(pa, 2); pa += __shfl_xor(pa, 4);
        if (j == 0) lg[r][rr] = pa;
    }

    float p[32];
    float acc[12] = {};
    float mx = -1e30f, lsum = 0.f, A = 0.f, Bc = 0.f;

    for (int s0 = 0; s0 < TDIM; s0 += 32) {
        __syncthreads();   // protects qs (iter 0) / ks,vs (later)
        for (int idx = tid; idx < 3072; idx += 128) {
            int s = idx & 31, d = idx >> 5;
            ks[s * STR + d] = kb[(size_t)d * TDIM + s0 + s];
            vs[s * STR + d] = vb[(size_t)d * TDIM + s0 + s];
        }
        __syncthreads();

        #pragma unroll
        for (int s = 0; s < 32; ++s) {
            float pa = 0.f;
            #pragma unroll
            for (int c = 0; c < 3; ++c) {
                float4 kv = *(const float4*)&ks[s * STR + d0 + 4 * c];
                pa += q[4*c]*kv.x + q[4*c+1]*kv.y + q[4*c+2]*kv.z + q[4*c+3]*kv.w;
            }
            pa += __shfl_xor(pa, 1); pa += __shfl_xor(pa, 2); pa += __shfl_xor(pa, 4);
            p[s] = pa;
        }

        float nm = mx;
        #pragma unroll
        for (int s = 0; s < 32; ++s) {
            int rel = min(max(row - (s0 + s) + WREL, 0), 2 * WREL);
            p[s] += lg[r][rel];
            nm = fmaxf(nm, p[s]);
        }
        float rs = __expf(mx - nm);
        mx = nm;
        if (rs != 1.f) {        // defer-rescale: skipped once max stabilizes
            for (int bb = j; bb < 19; bb += 8) band[r][bb] *= rs;
            lsum *= rs; A *= rs; Bc *= rs;
            #pragma unroll
            for (int jj = 0; jj < 12; ++jj) acc[jj] *= rs;
        }

        #pragma unroll
        for (int s = 0; s < 32; ++s) {
            float e = __expf(p[s] - nm);
            p[s] = e;
            lsum += e;
            int g = row - (s0 + s) + WREL;
            if (g <= 0) A += e;
            else if (g >= 2 * WREL) Bc += e;
            else if (j == 0) band[r][g - 1] = e;   // single writer globally
        }

        #pragma unroll
        for (int s = 0; s < 32; ++s) {
            float e = p[s];
            #pragma unroll
            for (int c = 0; c < 3; ++c) {
                float4 vv = *(const float4*)&vs[s * STR + d0 + 4 * c];
                acc[4*c]   += e * vv.x; acc[4*c+1] += e * vv.y;
                acc[4*c+2] += e * vv.z; acc[4*c+3] += e * vv.w;
            }
        }
    }

    // epilogue: rel-v contribution + normalize
    float o[12];
    #pragma unroll
    for (int jj = 0; jj < 12; ++jj)
        o[jj] = acc[jj] + A * erv[d0 + jj] + Bc * erv[2 * WREL * 96 + d0 + jj];
    for (int rel = 1; rel <= 19; ++rel) {
        float bv = band[r][rel - 1];
        #pragma unroll
        for (int jj = 0; jj < 12; ++jj)
            o[jj] += bv * erv[rel * 96 + d0 + jj];
    }
    float inv = 1.0f / lsum;

    // transpose via LDS -> coalesced store
    __syncthreads();
    float* osm = smem;                    // [96][17]
    #pragma unroll
    for (int jj = 0; jj < 12; ++jj)
        osm[(d0 + jj) * 17 + r] = o[jj] * inv;
    __syncthreads();
    float* ob = out + ((size_t)b * CDIM + h * 96) * TDIM + t0;
    for (int idx = tid; idx < 96 * 16; idx += 128) {
        int d = idx >> 4, t = idx & 15;
        ob[(size_t)d * TDIM + t] = osm[d * 17 + t];
    }
}

// ---------------------------------------------------------------------------
// Residual + channel LayerNorm (register-cached v).
// ---------------------------------------------------------------------------
__global__ __launch_bounds__(256) void ln_kernel(
    const float* __restrict__ xres, const float* __restrict__ y,
    const float* __restrict__ gamma, const float* __restrict__ beta,
    const float* __restrict__ mask, float* __restrict__ outp, int applymask)
{
    int b = blockIdx.y;
    int tl = threadIdx.x & 31;
    int g  = threadIdx.x >> 5;
    int t  = blockIdx.x * 32 + tl;
    int cb = g * 24;

    __shared__ float part[2][8][32];

    const float* xb = xres + (size_t)b * CDIM * TDIM + t;
    const float* yb = y    + (size_t)b * CDIM * TDIM + t;

    float vv[24];
    float s = 0.f, ss = 0.f;
    #pragma unroll
    for (int c = 0; c < 24; ++c) {
        float v = xb[(size_t)(cb + c) * TDIM] + yb[(size_t)(cb + c) * TDIM];
        vv[c] = v; s += v; ss += v * v;
    }
    part[0][g][tl] = s;
    part[1][g][tl] = ss;
    __syncthreads();
    float S = 0.f, SS = 0.f;
    #pragma unroll
    for (int gg = 0; gg < 8; ++gg) { S += part[0][gg][tl]; SS += part[1][gg][tl]; }
    float mean = S * (1.0f / 192.0f);
    float var  = SS * (1.0f / 192.0f) - mean * mean;
    float rstd = rsqrtf(var + 1e-5f);
    float mk = applymask ? mask[(size_t)b * TDIM + t] : 1.f;

    float* ob = outp + (size_t)b * CDIM * TDIM + t;
    #pragma unroll
    for (int c = 0; c < 24; ++c) {
        float rr = gamma[cb + c] * ((vv[c] - mean) * rstd) + beta[cb + c];
        if (applymask) rr *= mk;
        ob[(size_t)(cb + c) * TDIM] = rr;
    }
}

// ---------------------------------------------------------------------------
extern "C" void kernel_launch(void* const* d_in, const int* in_sizes, int n_in,
                              void* d_out, int out_size, void* d_ws, size_t ws_size,
                              hipStream_t stream)
{
    const float* x_in  = (const float*)d_in[0];
    const float* mask  = (const float*)d_in[1];
    const float* w_q   = (const float*)d_in[2];
    const float* b_q   = (const float*)d_in[3];
    const float* w_k   = (const float*)d_in[4];
    const float* b_k   = (const float*)d_in[5];
    const float* w_v   = (const float*)d_in[6];
    const float* b_v   = (const float*)d_in[7];
    const float* w_o   = (const float*)d_in[8];
    const float* b_o   = (const float*)d_in[9];
    const float* erk   = (const float*)d_in[10];
    const float* erv   = (const float*)d_in[11];
    const float* g1    = (const float*)d_in[12];
    const float* be1   = (const float*)d_in[13];
    const float* w_f1  = (const float*)d_in[14];
    const float* b_f1  = (const float*)d_in[15];
    const float* w_f2  = (const float*)d_in[16];
    const float* b_f2  = (const float*)d_in[17];
    const float* g2    = (const float*)d_in[18];
    const float* be2   = (const float*)d_in[19];

    char* wsb = (char*)d_ws;
    float* out = (float*)d_out;

    const unsigned short* WBQKV = (const unsigned short*)(wsb + OFFB_WQKV);
    const unsigned short* WBO   = (const unsigned short*)(wsb + OFFB_WO);
    const unsigned short* WBF1  = (const unsigned short*)(wsb + OFFB_WF1);
    const unsigned short* WBF2  = (const unsigned short*)(wsb + OFFB_WF2);
    const float*  BQKV  = (const float*)(wsb + OFFB_BQKV);
    float* QKVB = (float*)(wsb + OFFB_SHARED);
    float* ATTN = (float*)(wsb + OFFB_SHARED + SZB_QKV);
    float* H1   = (float*)(wsb + OFFB_SHARED);   // aliases QKV|ATTN (dead by then)
    float* YB   = (float*)(wsb + OFFB_Y);
    float* XCUR = (float*)(wsb + OFFB_XCUR);

    prep_kernel<<<dim3(1024, 5), 256, 0, stream>>>(w_q, w_k, w_v, w_o, w_f1, w_f2,
                                                   b_q, b_k, b_v, wsb);

    for (int l = 0; l < LNUM; ++l) {
        const float* xc = (l == 0) ? x_in : XCUR;

        // QKV projection (q weights/bias pre-scaled), input masked
        gemm_mfma<1, true, false, false><<<dim3(12, 9, 8), 256, 0, stream>>>(
            WBQKV + (size_t)l * 576 * 192, xc, BQKV + l * 576, mask, QKVB, 576, 192);

        attn_kernel<<<dim3(48, 2, 8), 128, 0, stream>>>(
            QKVB, erk + (size_t)l * NR * KCD, erv + (size_t)l * NR * KCD, ATTN);

        // output projection
        gemm_mfma<1, false, false, false><<<dim3(12, 3, 8), 256, 0, stream>>>(
            WBO + (size_t)l * 192 * 192, ATTN, b_o + l * 192, mask, YB, 192, 192);

        // x = LN(x + y)
        ln_kernel<<<dim3(24, 8), 256, 0, stream>>>(xc, YB, g1 + l * 192, be1 + l * 192,
                                                   mask, XCUR, 0);

        // FFN conv1 (K=3) + ReLU, input masked (H1 overwrites QKV/ATTN - dead)
        gemm_mfma<3, true, true, false><<<dim3(12, 12, 8), 256, 0, stream>>>(
            WBF1 + (size_t)l * 3 * 768 * 192, XCUR, b_f1 + l * FCH, mask, H1, 768, 192);

        // FFN conv2 (K=3), input masked, output masked
        gemm_mfma<3, true, false, true><<<dim3(12, 3, 8), 256, 0, stream>>>(
            WBF2 + (size_t)l * 3 * 192 * 768, H1, b_f2 + l * 192, mask, YB, 192, 768);

        bool last = (l == LNUM - 1);
        ln_kernel<<<dim3(24, 8), 256, 0, stream>>>(XCUR, YB, g2 + l * 192, be2 + l * 192,
                                                   mask, last ? out : XCUR, last ? 1 : 0);
    }
}

// Round 7
// 1988.541 us; speedup vs baseline: 2.5593x; 1.4558x over previous
//
#include <hip/hip_runtime.h>
#include <cstddef>
#include <cstdint>

// Problem constants
#define LNUM 6
#define CDIM 192
#define FCH 768
#define HNUM 2
#define WREL 10
#define BNUM 8
#define TDIM 768
#define KCD 96
#define NR 21   // 2W+1

typedef short s16x8 __attribute__((ext_vector_type(8)));
typedef float f32x4 __attribute__((ext_vector_type(4)));

__device__ __forceinline__ unsigned f2bf(float f) {
    unsigned u = __builtin_bit_cast(unsigned, f);
    u += 0x7FFF + ((u >> 16) & 1);          // round-to-nearest-even
    return u >> 16;
}
__device__ __forceinline__ float bflo(unsigned u) {   // low bf16 -> f32
    return __builtin_bit_cast(float, u << 16);
}
__device__ __forceinline__ float bfhi(unsigned u) {   // high bf16 -> f32
    return __builtin_bit_cast(float, u & 0xFFFF0000u);
}

// ---------------------------------------------------------------------------
// Workspace layout (BYTE offsets). Weights bf16 (ushort), activations fp32.
// ---------------------------------------------------------------------------
#define OFFB_WQKV   ((size_t)0)
#define SZB_WQKV    ((size_t)LNUM*576*192*2)
#define OFFB_WO     (OFFB_WQKV + SZB_WQKV)
#define SZB_WO      ((size_t)LNUM*192*192*2)
#define OFFB_WF1    (OFFB_WO + SZB_WO)
#define SZB_WF1     ((size_t)LNUM*3*768*192*2)
#define OFFB_WF2    (OFFB_WF1 + SZB_WF1)
#define SZB_WF2     ((size_t)LNUM*3*192*768*2)
#define OFFB_BQKV   (OFFB_WF2 + SZB_WF2)
#define SZB_BQKV    ((size_t)LNUM*576*4)
#define OFFB_SHARED (OFFB_BQKV + SZB_BQKV)
#define SZB_QKV     ((size_t)BNUM*576*TDIM*4)
#define SZB_ACT     ((size_t)BNUM*CDIM*TDIM*4)
#define SZB_SHARED  ((size_t)BNUM*768*TDIM*4)   // {QKV|ATTN} == H1, time-multiplexed
#define OFFB_Y      (OFFB_SHARED + SZB_SHARED)
#define OFFB_XCUR   (OFFB_Y + SZB_ACT)

// ---------------------------------------------------------------------------
// Prep: weights -> bf16 [KW][M][Cin] per layer; qkv bias stacked (q scaled).
// blockIdx.y = job: 0=QKV 1=O 2=F1 3=F2 4=bias
// ---------------------------------------------------------------------------
__global__ __launch_bounds__(256) void prep_kernel(
    const float* __restrict__ wq, const float* __restrict__ wk,
    const float* __restrict__ wv, const float* __restrict__ wo,
    const float* __restrict__ wf1, const float* __restrict__ wf2,
    const float* __restrict__ bq, const float* __restrict__ bk,
    const float* __restrict__ bv, char* __restrict__ wsb)
{
    const float qscale = 0.10206207261596575f; // 1/sqrt(96)
    int job = blockIdx.y;
    int stride = gridDim.x * 256;
    int base = blockIdx.x * 256 + threadIdx.x;

    if (job == 0) {
        unsigned short* dst = (unsigned short*)(wsb + OFFB_WQKV);
        const int N = LNUM * 576 * 192;
        for (int idx = base; idx < N; idx += stride) {
            int c = idx % 192;
            int m = (idx / 192) % 576;
            int l = idx / (192 * 576);
            float v;
            if (m < 192)      v = wq[((size_t)l*192 + m)*192 + c] * qscale;
            else if (m < 384) v = wk[((size_t)l*192 + (m-192))*192 + c];
            else              v = wv[((size_t)l*192 + (m-384))*192 + c];
            dst[idx] = (unsigned short)f2bf(v);
        }
    } else if (job == 1) {
        unsigned short* dst = (unsigned short*)(wsb + OFFB_WO);
        const int N = LNUM * 192 * 192;
        for (int idx = base; idx < N; idx += stride)
            dst[idx] = (unsigned short)f2bf(wo[idx]);
    } else if (job == 2) {
        unsigned short* dst = (unsigned short*)(wsb + OFFB_WF1);
        const int N = LNUM * 3 * 768 * 192;
        for (int idx = base; idx < N; idx += stride) {
            int c = idx % 192;
            int m = (idx / 192) % 768;
            int k = (idx / (192*768)) % 3;
            int l = idx / (192*768*3);
            dst[idx] = (unsigned short)f2bf(wf1[(((size_t)l*768 + m)*192 + c)*3 + k]);
        }
    } else if (job == 3) {
        unsigned short* dst = (unsigned short*)(wsb + OFFB_WF2);
        const int N = LNUM * 3 * 192 * 768;
        for (int idx = base; idx < N; idx += stride) {
            int c = idx % 768;
            int m = (idx / 768) % 192;
            int k = (idx / (768*192)) % 3;
            int l = idx / (768*192*3);
            dst[idx] = (unsigned short)f2bf(wf2[(((size_t)l*192 + m)*768 + c)*3 + k]);
        }
    } else {
        float* dst = (float*)(wsb + OFFB_BQKV);
        const int N = LNUM * 576;
        for (int idx = base; idx < N; idx += stride) {
            int j = idx % 576, l = idx / 576;
            float v;
            if (j < 192)      v = bq[l*192 + j] * qscale;
            else if (j < 384) v = bk[l*192 + j - 192];
            else              v = bv[l*192 + j - 384];
            dst[idx] = v;
        }
    }
}

// ---------------------------------------------------------------------------
// bf16 MFMA GEMM / conv1d (unchanged from R6 - proven).
// ---------------------------------------------------------------------------
template<int KW, bool MASKIN, bool RELU, bool OUTMASK>
__global__ __launch_bounds__(256) void gemm_mfma(
    const unsigned short* __restrict__ Wb, const float* __restrict__ Xg,
    const float* __restrict__ bias, const float* __restrict__ mask,
    float* __restrict__ Y, int M, int Cin)
{
    constexpr int H = KW / 2;
    constexpr int ROWS = 64 + 2 * H;
    constexpr int CC = 64;
    constexpr int CP = 72;
    constexpr int SMEM_BYTES = (ROWS + KW * 64) * CP * 2;
    __shared__ __align__(16) char smem_raw[SMEM_BYTES];
    unsigned short (*xs)[CP] = (unsigned short(*)[CP])smem_raw;
    unsigned short (*wsm)[64][CP] = (unsigned short(*)[64][CP])(smem_raw + ROWS * CP * 2);

    int b  = blockIdx.z;
    int t0 = blockIdx.x * 64;
    int m0 = blockIdx.y * 64;
    int tid  = threadIdx.x;
    int wave = tid >> 6, lane = tid & 63;
    int wr = wave >> 1, wc = wave & 1;
    int lrow = lane & 15, lkg = lane >> 4;

    const float* Xb = Xg + (size_t)b * Cin * TDIM;
    const float* mb = mask + (size_t)b * TDIM;

    f32x4 acc[2][2];
    #pragma unroll
    for (int i = 0; i < 2; ++i)
        #pragma unroll
        for (int j = 0; j < 2; ++j)
            acc[i][j] = f32x4{0.f, 0.f, 0.f, 0.f};

    for (int c0 = 0; c0 < Cin; c0 += CC) {
        __syncthreads();
        for (int idx = tid; idx < ROWS * CC; idx += 256) {
            int c = idx / ROWS;
            int tt = idx - c * ROWS;
            int tg = t0 + tt - H;
            float v = 0.f;
            if (tg >= 0 && tg < TDIM) {
                v = Xb[(size_t)(c0 + c) * TDIM + tg];
                if (MASKIN) v *= mb[tg];
            }
            xs[tt][c] = (unsigned short)f2bf(v);
        }
        const unsigned short* Wc = Wb + c0;
        for (int idx = tid; idx < KW * 64 * (CC / 4); idx += 256) {
            int k = idx / (64 * (CC / 4));
            int rem = idx - k * 64 * (CC / 4);
            int m = rem >> 4;
            int c4 = rem & 15;
            *(uint2*)&wsm[k][m][c4 * 4] =
                *(const uint2*)(Wc + ((size_t)k * M + m0 + m) * Cin + c4 * 4);
        }
        __syncthreads();

        #pragma unroll
        for (int k = 0; k < KW; ++k) {
            #pragma unroll
            for (int ks = 0; ks < CC / 32; ++ks) {
                s16x8 a0 = *(const s16x8*)&xs[32*wr +  0 + lrow + k][ks*32 + lkg*8];
                s16x8 a1 = *(const s16x8*)&xs[32*wr + 16 + lrow + k][ks*32 + lkg*8];
                s16x8 b0 = *(const s16x8*)&wsm[k][32*wc +  0 + lrow][ks*32 + lkg*8];
                s16x8 b1 = *(const s16x8*)&wsm[k][32*wc + 16 + lrow][ks*32 + lkg*8];
                acc[0][0] = __builtin_amdgcn_mfma_f32_16x16x32_bf16(a0, b0, acc[0][0], 0, 0, 0);
                acc[0][1] = __builtin_amdgcn_mfma_f32_16x16x32_bf16(a0, b1, acc[0][1], 0, 0, 0);
                acc[1][0] = __builtin_amdgcn_mfma_f32_16x16x32_bf16(a1, b0, acc[1][0], 0, 0, 0);
                acc[1][1] = __builtin_amdgcn_mfma_f32_16x16x32_bf16(a1, b1, acc[1][1], 0, 0, 0);
            }
        }
    }

    __syncthreads();
    float* tile = (float*)smem_raw;        // [64][65]
    #pragma unroll
    for (int i = 0; i < 2; ++i) {
        #pragma unroll
        for (int j = 0; j < 2; ++j) {
            int ml = 32 * wc + 16 * j + lrow;
            float bv = bias[m0 + ml];
            #pragma unroll
            for (int r = 0; r < 4; ++r) {
                int tl = 32 * wr + 16 * i + lkg * 4 + r;
                float v = acc[i][j][r] + bv;
                if (RELU) v = fmaxf(v, 0.f);
                if (OUTMASK) v *= mb[t0 + tl];
                tile[tl * 65 + ml] = v;
            }
        }
    }
    __syncthreads();
    for (int idx = tid; idx < 64 * 16; idx += 256) {
        int m = idx >> 4, tq = (idx & 15) * 4;
        float4 o;
        o.x = tile[(tq + 0) * 65 + m];
        o.y = tile[(tq + 1) * 65 + m];
        o.z = tile[(tq + 2) * 65 + m];
        o.w = tile[(tq + 3) * 65 + m];
        *(float4*)&Y[((size_t)b * M + m0 + m) * TDIM + t0 + tq] = o;
    }
}

// ---------------------------------------------------------------------------
// MFMA flash attention. 64 q-rows/block, 4 waves x 16 rows, 256 threads.
// S^T = mfma(K, Q) per s-half (swapped operands -> row-softmax is lane-local
// regs + 2 shfl).  PV = mfma(P_hi, V) + mfma(P_lo, V) (bf16 hi/lo split).
// Rel-key bias via lg[64][21]; rel-v via band buckets + clipped partials.
// K/V staged bf16-packed, async-split (T14): next tile's global loads issued
// before computing current tile.
// Grid dim3(16,12): x = b*2+h (XCD locality for K/V), y = t-tile.
// ---------------------------------------------------------------------------
__global__ __launch_bounds__(256) void attn_mfma(
    const float* __restrict__ qkv, const float* __restrict__ erk,
    const float* __restrict__ erv, float* __restrict__ out)
{
    constexpr int QP = 52;   // u32 row stride of q tile (96 bf16 + pad)
    constexpr int KP = 52;   // u32 row stride of k tile
    constexpr int VP = 20;   // u32 row stride of v^T tile (32 bf16 + pad)
    constexpr int PP = 36;   // u32 row stride of P (hi 16 | lo 16 | pad 4)

    __shared__ __align__(16) unsigned qs_lds[64 * QP];
    __shared__ __align__(16) unsigned ks_lds[32 * KP];
    __shared__ __align__(16) unsigned vt_lds[96 * VP];
    __shared__ __align__(16) unsigned p_lds[64 * PP];
    __shared__ float band_lds[64 * 20];
    __shared__ float lg_lds[64 * NR];
    __shared__ float ervs[NR * 96];
    __shared__ float rs_lds[64];
    __shared__ float statL[64], statA[64], statB[64];

    int bh = blockIdx.x;
    int b = bh >> 1, h = bh & 1;
    int t0 = blockIdx.y * 64;
    int tid = threadIdx.x;
    int w = tid >> 6, l = tid & 63;
    int lt = l & 15, g = l >> 4;
    int tblk = w * 16 + lt;              // this lane's t (score phase role)
    int rowg = t0 + tblk;

    const float* qb = qkv + ((size_t)b * 576 + h * 96) * TDIM;
    const float* kb = qb + (size_t)192 * TDIM;
    const float* vb = qb + (size_t)384 * TDIM;

    // ---- phase 0: stage Q (f32->bf16 packed), erv, zero band ----
    for (int idx = tid; idx < 64 * 48; idx += 256) {
        int t = idx & 63, dp = idx >> 6;
        float f0 = qb[(size_t)(2*dp) * TDIM + t0 + t];
        float f1 = qb[(size_t)(2*dp + 1) * TDIM + t0 + t];
        qs_lds[t * QP + dp] = f2bf(f0) | (f2bf(f1) << 16);
    }
    for (int idx = tid; idx < NR * 96; idx += 256) ervs[idx] = erv[idx];
    for (int idx = tid; idx < 64 * 20; idx += 256) band_lds[idx] = 0.f;
    __syncthreads();

    // ---- phase 0b: rel-key logits lg[t][r] from bf16 q ----
    for (int idx = tid; idx < 64 * NR; idx += 256) {
        int t = idx & 63, r = idx >> 6;
        const float* ek = erk + r * 96;
        float s = 0.f;
        #pragma unroll
        for (int dp = 0; dp < 48; ++dp) {
            unsigned u = qs_lds[t * QP + dp];
            s += bflo(u) * ek[2*dp] + bfhi(u) * ek[2*dp + 1];
        }
        lg_lds[t * NR + r] = s;
    }
    __syncthreads();

    // ---- per-wave persistent Q B-frags ----
    s16x8 qf[3];
    #pragma unroll
    for (int j = 0; j < 3; ++j)
        qf[j] = *(const s16x8*)&qs_lds[tblk * QP + 16*j + 4*g];

    // ---- accumulators ----
    f32x4 o[6];
    #pragma unroll
    for (int dt = 0; dt < 6; ++dt) o[dt] = f32x4{0.f,0.f,0.f,0.f};
    float m_old = -1e30f, lsum_p = 0.f, A_p = 0.f, B_p = 0.f;

    // ---- staging registers (tile prefetch) ----
    float kf0[6], kf1[6];
    float2 vv[6];
    int ksr[6], kdp[6], vdr[6], vsp[6];
    #pragma unroll
    for (int p = 0; p < 6; ++p) {
        int i2 = tid + p * 256;
        ksr[p] = i2 & 31; kdp[p] = i2 >> 5;
        vdr[p] = i2 >> 4; vsp[p] = i2 & 15;
    }
    // preload tile 0
    #pragma unroll
    for (int p = 0; p < 6; ++p) {
        kf0[p] = kb[(size_t)(2*kdp[p]) * TDIM + ksr[p]];
        kf1[p] = kb[(size_t)(2*kdp[p] + 1) * TDIM + ksr[p]];
        vv[p]  = *(const float2*)&vb[(size_t)vdr[p] * TDIM + 2*vsp[p]];
    }

    for (int tile = 0; tile < 24; ++tile) {
        int s0 = tile * 32;
        __syncthreads();                         // prior tile's K/V reads done
        #pragma unroll
        for (int p = 0; p < 6; ++p) {
            ks_lds[ksr[p] * KP + kdp[p]] = f2bf(kf0[p]) | (f2bf(kf1[p]) << 16);
            vt_lds[vdr[p] * VP + vsp[p]] = f2bf(vv[p].x) | (f2bf(vv[p].y) << 16);
        }
        if (tile < 23) {
            int sn = s0 + 32;
            #pragma unroll
            for (int p = 0; p < 6; ++p) {
                kf0[p] = kb[(size_t)(2*kdp[p]) * TDIM + sn + ksr[p]];
                kf1[p] = kb[(size_t)(2*kdp[p] + 1) * TDIM + sn + ksr[p]];
                vv[p]  = *(const float2*)&vb[(size_t)vdr[p] * TDIM + sn + 2*vsp[p]];
            }
        }
        __syncthreads();                         // K/V ready

        // QK^T (swapped): S^T[s][t]
        f32x4 st0 = f32x4{0.f,0.f,0.f,0.f}, st1 = f32x4{0.f,0.f,0.f,0.f};
        #pragma unroll
        for (int j = 0; j < 3; ++j) {
            s16x8 a0 = *(const s16x8*)&ks_lds[(     lt) * KP + 16*j + 4*g];
            s16x8 a1 = *(const s16x8*)&ks_lds[(16 + lt) * KP + 16*j + 4*g];
            st0 = __builtin_amdgcn_mfma_f32_16x16x32_bf16(a0, qf[j], st0, 0, 0, 0);
            st1 = __builtin_amdgcn_mfma_f32_16x16x32_bf16(a1, qf[j], st1, 0, 0, 0);
        }

        // bias + online softmax (lane: t = tblk, s = hh*16 + 4g + r)
        float p8[8];
        #pragma unroll
        for (int hh = 0; hh < 2; ++hh)
            #pragma unroll
            for (int r = 0; r < 4; ++r) {
                int sg = s0 + hh*16 + 4*g + r;
                int rel = min(max(rowg - sg + WREL, 0), 2*WREL);
                float sv = (hh == 0) ? st0[r] : st1[r];
                p8[hh*4 + r] = sv + lg_lds[tblk * NR + rel];
            }
        float mxn = m_old;
        #pragma unroll
        for (int i = 0; i < 8; ++i) mxn = fmaxf(mxn, p8[i]);
        mxn = fmaxf(mxn, __shfl_xor(mxn, 16));
        mxn = fmaxf(mxn, __shfl_xor(mxn, 32));
        float rs = __expf(m_old - mxn);
        m_old = mxn;
        if (g == 0) rs_lds[tblk] = rs;
        if (__any(rs != 1.0f)) {
            for (int i = l; i < 16 * 19; i += 64) {
                int tt = i / 19, rr = i % 19;
                band_lds[(w*16 + tt) * 20 + rr] *= rs_lds[w*16 + tt];
            }
            lsum_p *= rs; A_p *= rs; B_p *= rs;
            float rsg[4];
            #pragma unroll
            for (int r = 0; r < 4; ++r) rsg[r] = rs_lds[w*16 + 4*g + r];
            #pragma unroll
            for (int dt = 0; dt < 6; ++dt)
                #pragma unroll
                for (int r = 0; r < 4; ++r) o[dt][r] *= rsg[r];
        }

        float e8[8];
        #pragma unroll
        for (int hh = 0; hh < 2; ++hh)
            #pragma unroll
            for (int r = 0; r < 4; ++r) {
                int i = hh*4 + r;
                float e = __expf(p8[i] - mxn);
                e8[i] = e;
                lsum_p += e;
                int grel = rowg - (s0 + hh*16 + 4*g + r) + WREL;
                if (grel <= 0) A_p += e;
                else if (grel >= 2*WREL) B_p += e;
                else band_lds[tblk * 20 + grel - 1] = e;   // unique writer
            }

        // pack P hi/lo -> LDS
        #pragma unroll
        for (int hh = 0; hh < 2; ++hh)
            #pragma unroll
            for (int r2 = 0; r2 < 2; ++r2) {
                float e0 = e8[hh*4 + 2*r2], e1 = e8[hh*4 + 2*r2 + 1];
                unsigned h0 = f2bf(e0), h1 = f2bf(e1);
                float lo0 = e0 - bflo(h0 << 16 >> 16 << 16 ? h0 : h0); // placeholder avoided below
                lo0 = e0 - __builtin_bit_cast(float, h0 << 16);
                float lo1 = e1 - __builtin_bit_cast(float, h1 << 16);
                int s2 = hh*8 + g*2 + r2;
                p_lds[tblk * PP + s2]      = h0 | (h1 << 16);
                p_lds[tblk * PP + 16 + s2] = f2bf(lo0) | (f2bf(lo1) << 16);
            }

        // PV: O[t][d] += P * V  (hi + lo chains)
        s16x8 pa_h = *(const s16x8*)&p_lds[tblk * PP + 4*g];
        s16x8 pa_l = *(const s16x8*)&p_lds[tblk * PP + 16 + 4*g];
        #pragma unroll
        for (int dt = 0; dt < 6; ++dt) {
            s16x8 vf = *(const s16x8*)&vt_lds[(16*dt + lt) * VP + 4*g];
            o[dt] = __builtin_amdgcn_mfma_f32_16x16x32_bf16(pa_h, vf, o[dt], 0, 0, 0);
            o[dt] = __builtin_amdgcn_mfma_f32_16x16x32_bf16(pa_l, vf, o[dt], 0, 0, 0);
        }
    }

    // ---- epilogue ----
    lsum_p += __shfl_xor(lsum_p, 16); lsum_p += __shfl_xor(lsum_p, 32);
    A_p    += __shfl_xor(A_p, 16);    A_p    += __shfl_xor(A_p, 32);
    B_p    += __shfl_xor(B_p, 16);    B_p    += __shfl_xor(B_p, 32);
    if (g == 0) { statL[tblk] = lsum_p; statA[tblk] = A_p; statB[tblk] = B_p; }

    float* ob = out + ((size_t)b * CDIM + h * 96) * TDIM;
    #pragma unroll
    for (int r = 0; r < 4; ++r) {
        int tt = w*16 + 4*g + r;                 // epilogue t (C/D row role)
        float Ls = statL[tt], Av = statA[tt], Bv = statB[tt];
        float inv = 1.0f / Ls;
        float bnd[19];
        #pragma unroll
        for (int rel = 1; rel <= 19; ++rel) bnd[rel-1] = band_lds[tt * 20 + rel - 1];
        #pragma unroll
        for (int dt = 0; dt < 6; ++dt) {
            int d = 16*dt + lt;
            float val = o[dt][r] + Av * ervs[d] + Bv * ervs[2*WREL*96 + d];
            #pragma unroll
            for (int rel = 1; rel <= 19; ++rel)
                val += bnd[rel-1] * ervs[rel*96 + d];
            o[dt][r] = val * inv;
        }
    }
    #pragma unroll
    for (int dt = 0; dt < 6; ++dt) {
        int d = 16*dt + lt;
        float4 st4 = make_float4(o[dt][0], o[dt][1], o[dt][2], o[dt][3]);
        *(float4*)&ob[(size_t)d * TDIM + t0 + w*16 + 4*g] = st4;
    }
}

// ---------------------------------------------------------------------------
// Residual + channel LayerNorm (unchanged from R6).
// ---------------------------------------------------------------------------
__global__ __launch_bounds__(256) void ln_kernel(
    const float* __restrict__ xres, const float* __restrict__ y,
    const float* __restrict__ gamma, const float* __restrict__ beta,
    const float* __restrict__ mask, float* __restrict__ outp, int applymask)
{
    int b = blockIdx.y;
    int tl = threadIdx.x & 31;
    int g  = threadIdx.x >> 5;
    int t  = blockIdx.x * 32 + tl;
    int cb = g * 24;

    __shared__ float part[2][8][32];

    const float* xb = xres + (size_t)b * CDIM * TDIM + t;
    const float* yb = y    + (size_t)b * CDIM * TDIM + t;

    float vv[24];
    float s = 0.f, ss = 0.f;
    #pragma unroll
    for (int c = 0; c < 24; ++c) {
        float v = xb[(size_t)(cb + c) * TDIM] + yb[(size_t)(cb + c) * TDIM];
        vv[c] = v; s += v; ss += v * v;
    }
    part[0][g][tl] = s;
    part[1][g][tl] = ss;
    __syncthreads();
    float S = 0.f, SS = 0.f;
    #pragma unroll
    for (int gg = 0; gg < 8; ++gg) { S += part[0][gg][tl]; SS += part[1][gg][tl]; }
    float mean = S * (1.0f / 192.0f);
    float var  = SS * (1.0f / 192.0f) - mean * mean;
    float rstd = rsqrtf(var + 1e-5f);
    float mk = applymask ? mask[(size_t)b * TDIM + t] : 1.f;

    float* ob = outp + (size_t)b * CDIM * TDIM + t;
    #pragma unroll
    for (int c = 0; c < 24; ++c) {
        float rr = gamma[cb + c] * ((vv[c] - mean) * rstd) + beta[cb + c];
        if (applymask) rr *= mk;
        ob[(size_t)(cb + c) * TDIM] = rr;
    }
}

// ---------------------------------------------------------------------------
extern "C" void kernel_launch(void* const* d_in, const int* in_sizes, int n_in,
                              void* d_out, int out_size, void* d_ws, size_t ws_size,
                              hipStream_t stream)
{
    const float* x_in  = (const float*)d_in[0];
    const float* mask  = (const float*)d_in[1];
    const float* w_q   = (const float*)d_in[2];
    const float* b_q   = (const float*)d_in[3];
    const float* w_k   = (const float*)d_in[4];
    const float* b_k   = (const float*)d_in[5];
    const float* w_v   = (const float*)d_in[6];
    const float* b_v   = (const float*)d_in[7];
    const float* w_o   = (const float*)d_in[8];
    const float* b_o   = (const float*)d_in[9];
    const float* erk   = (const float*)d_in[10];
    const float* erv   = (const float*)d_in[11];
    const float* g1    = (const float*)d_in[12];
    const float* be1   = (const float*)d_in[13];
    const float* w_f1  = (const float*)d_in[14];
    const float* b_f1  = (const float*)d_in[15];
    const float* w_f2  = (const float*)d_in[16];
    const float* b_f2  = (const float*)d_in[17];
    const float* g2    = (const float*)d_in[18];
    const float* be2   = (const float*)d_in[19];

    char* wsb = (char*)d_ws;
    float* out = (float*)d_out;

    const unsigned short* WBQKV = (const unsigned short*)(wsb + OFFB_WQKV);
    const unsigned short* WBO   = (const unsigned short*)(wsb + OFFB_WO);
    const unsigned short* WBF1  = (const unsigned short*)(wsb + OFFB_WF1);
    const unsigned short* WBF2  = (const unsigned short*)(wsb + OFFB_WF2);
    const float*  BQKV  = (const float*)(wsb + OFFB_BQKV);
    float* QKVB = (float*)(wsb + OFFB_SHARED);
    float* ATTN = (float*)(wsb + OFFB_SHARED + SZB_QKV);
    float* H1   = (float*)(wsb + OFFB_SHARED);   // aliases QKV|ATTN (dead by then)
    float* YB   = (float*)(wsb + OFFB_Y);
    float* XCUR = (float*)(wsb + OFFB_XCUR);

    prep_kernel<<<dim3(1024, 5), 256, 0, stream>>>(w_q, w_k, w_v, w_o, w_f1, w_f2,
                                                   b_q, b_k, b_v, wsb);

    for (int l = 0; l < LNUM; ++l) {
        const float* xc = (l == 0) ? x_in : XCUR;

        gemm_mfma<1, true, false, false><<<dim3(12, 9, 8), 256, 0, stream>>>(
            WBQKV + (size_t)l * 576 * 192, xc, BQKV + l * 576, mask, QKVB, 576, 192);

        attn_mfma<<<dim3(16, 12), 256, 0, stream>>>(
            QKVB, erk + (size_t)l * NR * KCD, erv + (size_t)l * NR * KCD, ATTN);

        gemm_mfma<1, false, false, false><<<dim3(12, 3, 8), 256, 0, stream>>>(
            WBO + (size_t)l * 192 * 192, ATTN, b_o + l * 192, mask, YB, 192, 192);

        ln_kernel<<<dim3(24, 8), 256, 0, stream>>>(xc, YB, g1 + l * 192, be1 + l * 192,
                                                   mask, XCUR, 0);

        gemm_mfma<3, true, true, false><<<dim3(12, 12, 8), 256, 0, stream>>>(
            WBF1 + (size_t)l * 3 * 768 * 192, XCUR, b_f1 + l * FCH, mask, H1, 768, 192);

        gemm_mfma<3, true, false, true><<<dim3(12, 3, 8), 256, 0, stream>>>(
            WBF2 + (size_t)l * 3 * 192 * 768, H1, b_f2 + l * 192, mask, YB, 192, 768);

        bool last = (l == LNUM - 1);
        ln_kernel<<<dim3(24, 8), 256, 0, stream>>>(XCUR, YB, g2 + l * 192, be2 + l * 192,
                                                   mask, last ? out : XCUR, last ? 1 : 0);
    }
}

// Round 8
// 963.625 us; speedup vs baseline: 5.2813x; 2.0636x over previous
//
#include <hip/hip_runtime.h>
#include <cstddef>
#include <cstdint>

// Problem constants
#define LNUM 6
#define CDIM 192
#define FCH 768
#define HNUM 2
#define WREL 10
#define BNUM 8
#define TDIM 768
#define KCD 96
#define NR 21   // 2W+1

typedef short s16x8 __attribute__((ext_vector_type(8)));
typedef float f32x4 __attribute__((ext_vector_type(4)));

__device__ __forceinline__ unsigned f2bf(float f) {
    unsigned u = __builtin_bit_cast(unsigned, f);
    u += 0x7FFF + ((u >> 16) & 1);          // round-to-nearest-even
    return u >> 16;
}
__device__ __forceinline__ float bflo(unsigned u) {
    return __builtin_bit_cast(float, u << 16);
}
__device__ __forceinline__ float bfhi(unsigned u) {
    return __builtin_bit_cast(float, u & 0xFFFF0000u);
}

// ---------------------------------------------------------------------------
// Workspace layout (BYTE offsets). Weights bf16; QKV/ATTN/H1 bf16; YB/XCUR f32.
// ---------------------------------------------------------------------------
#define OFFB_WQKV   ((size_t)0)
#define SZB_WQKV    ((size_t)LNUM*576*192*2)
#define OFFB_WO     (OFFB_WQKV + SZB_WQKV)
#define SZB_WO      ((size_t)LNUM*192*192*2)
#define OFFB_WF1    (OFFB_WO + SZB_WO)
#define SZB_WF1     ((size_t)LNUM*3*768*192*2)
#define OFFB_WF2    (OFFB_WF1 + SZB_WF1)
#define SZB_WF2     ((size_t)LNUM*3*192*768*2)
#define OFFB_BQKV   (OFFB_WF2 + SZB_WF2)
#define SZB_BQKV    ((size_t)LNUM*576*4)
#define OFFB_SHARED (OFFB_BQKV + SZB_BQKV)
#define SZB_QKV     ((size_t)BNUM*576*TDIM*2)     // bf16
#define SZB_ATTN    ((size_t)BNUM*CDIM*TDIM*2)    // bf16
#define SZB_SHARED  ((size_t)BNUM*768*TDIM*2)     // == QKV+ATTN == H1 (bf16)
#define OFFB_Y      (OFFB_SHARED + SZB_SHARED)
#define SZB_YF      ((size_t)BNUM*CDIM*TDIM*4)    // f32
#define OFFB_XCUR   (OFFB_Y + SZB_YF)
// total ~ 32 MB

// ---------------------------------------------------------------------------
// Prep: weights -> bf16 [KW][M][Cin] per layer; qkv bias stacked (q scaled).
// blockIdx.y = job: 0=QKV 1=O 2=F1 3=F2 4=bias
// ---------------------------------------------------------------------------
__global__ __launch_bounds__(256) void prep_kernel(
    const float* __restrict__ wq, const float* __restrict__ wk,
    const float* __restrict__ wv, const float* __restrict__ wo,
    const float* __restrict__ wf1, const float* __restrict__ wf2,
    const float* __restrict__ bq, const float* __restrict__ bk,
    const float* __restrict__ bv, char* __restrict__ wsb)
{
    const float qscale = 0.10206207261596575f; // 1/sqrt(96)
    int job = blockIdx.y;
    int stride = gridDim.x * 256;
    int base = blockIdx.x * 256 + threadIdx.x;

    if (job == 0) {
        unsigned short* dst = (unsigned short*)(wsb + OFFB_WQKV);
        const int N = LNUM * 576 * 192;
        for (int idx = base; idx < N; idx += stride) {
            int c = idx % 192;
            int m = (idx / 192) % 576;
            int l = idx / (192 * 576);
            float v;
            if (m < 192)      v = wq[((size_t)l*192 + m)*192 + c] * qscale;
            else if (m < 384) v = wk[((size_t)l*192 + (m-192))*192 + c];
            else              v = wv[((size_t)l*192 + (m-384))*192 + c];
            dst[idx] = (unsigned short)f2bf(v);
        }
    } else if (job == 1) {
        unsigned short* dst = (unsigned short*)(wsb + OFFB_WO);
        const int N = LNUM * 192 * 192;
        for (int idx = base; idx < N; idx += stride)
            dst[idx] = (unsigned short)f2bf(wo[idx]);
    } else if (job == 2) {
        unsigned short* dst = (unsigned short*)(wsb + OFFB_WF1);
        const int N = LNUM * 3 * 768 * 192;
        for (int idx = base; idx < N; idx += stride) {
            int c = idx % 192;
            int m = (idx / 192) % 768;
            int k = (idx / (192*768)) % 3;
            int l = idx / (192*768*3);
            dst[idx] = (unsigned short)f2bf(wf1[(((size_t)l*768 + m)*192 + c)*3 + k]);
        }
    } else if (job == 3) {
        unsigned short* dst = (unsigned short*)(wsb + OFFB_WF2);
        const int N = LNUM * 3 * 192 * 768;
        for (int idx = base; idx < N; idx += stride) {
            int c = idx % 768;
            int m = (idx / 768) % 192;
            int k = (idx / (768*192)) % 3;
            int l = idx / (768*192*3);
            dst[idx] = (unsigned short)f2bf(wf2[(((size_t)l*192 + m)*768 + c)*3 + k]);
        }
    } else {
        float* dst = (float*)(wsb + OFFB_BQKV);
        const int N = LNUM * 576;
        for (int idx = base; idx < N; idx += stride) {
            int j = idx % 576, l = idx / 576;
            float v;
            if (j < 192)      v = bq[l*192 + j] * qscale;
            else if (j < 384) v = bk[l*192 + j - 192];
            else              v = bv[l*192 + j - 384];
            dst[idx] = v;
        }
    }
}

// ---------------------------------------------------------------------------
// bf16 MFMA GEMM / conv1d, v2: T14 register-prefetch pipeline, NB batches
// per block (W staged once per K-chunk for the group), conflict-free X
// staging (bank = 4q + c/2 -> 2 lanes/bank), bf16 or f32 input/output.
// Wb bf16 [KW][M][Cin]; X [B][Cin][T] (f32 or bf16); Y [B][M][T] (f32/bf16).
// ---------------------------------------------------------------------------
template<int KW, bool INBF, bool MASKIN, bool RELU, bool OUTMASK, bool OUTBF, int NB>
__global__ __launch_bounds__(256) void gemm_mfma(
    const unsigned short* __restrict__ Wb, const void* __restrict__ Xg_,
    const float* __restrict__ bias, const float* __restrict__ mask,
    void* __restrict__ Yg_, int M, int Cin)
{
    static_assert(!(INBF && MASKIN), "bf16 inputs are pre-masked");
    constexpr int H = KW / 2;
    constexpr int ROWS = 64 + 2 * H;
    constexpr int CC = 64;
    constexpr int CP = 72;
    constexpr int SMEM = (ROWS + KW * 64) * CP * 2;   // >= 64*65*4 (epilogue tile)
    __shared__ __align__(16) char smem_raw[SMEM];
    unsigned short (*xs)[CP] = (unsigned short(*)[CP])smem_raw;
    unsigned short (*wsm)[CP] = (unsigned short(*)[CP])(smem_raw + ROWS * CP * 2);

    const float* Xf = (const float*)Xg_;
    const unsigned short* Xu = (const unsigned short*)Xg_;
    float* Yf = (float*)Yg_;
    unsigned short* Yu = (unsigned short*)Yg_;

    int bz = blockIdx.z;
    int t0 = blockIdx.x * 64;
    int m0 = blockIdx.y * 64;
    int tid  = threadIdx.x;
    int wave = tid >> 6, lane = tid & 63;
    int wr = wave >> 1, wc = wave & 1;
    int lrow = lane & 15, lkg = lane >> 4;

    int cq  = tid & 15;       // t sub-index (stride-16 rows)
    int cc0 = tid >> 4;       // c base (0..15), + 16p
    int hc  = tid >> 1, hcol = tid & 1;   // halo task (threads < 128)

    f32x4 acc[NB][2][2];
    #pragma unroll
    for (int bi = 0; bi < NB; ++bi)
        #pragma unroll
        for (int i = 0; i < 2; ++i)
            #pragma unroll
            for (int j = 0; j < 2; ++j)
                acc[bi][i][j] = f32x4{0.f, 0.f, 0.f, 0.f};

    // prefetch registers
    float xf[4][4]; unsigned short xb[4][4];
    float mf[4]; float xhf = 0.f; unsigned short xhb = 0; float mh = 0.f;
    uint2 wreg[KW * 4];

    auto loadX = [&](int bi, int c0) {
        size_t bb = (size_t)(bz * NB + bi);
        if constexpr (!INBF) {
            const float* Xb = Xf + bb * Cin * TDIM;
            #pragma unroll
            for (int p = 0; p < 4; ++p)
                #pragma unroll
                for (int j = 0; j < 4; ++j)
                    xf[p][j] = Xb[(size_t)(c0 + cc0 + 16*p) * TDIM + t0 + cq + 16*j];
            if constexpr (MASKIN) {
                const float* mbb = mask + bb * TDIM;
                #pragma unroll
                for (int j = 0; j < 4; ++j) mf[j] = mbb[t0 + cq + 16*j];
            }
            if constexpr (KW == 3) {
                if (tid < 128) {
                    int tg = hcol ? t0 + 64 : t0 - 1;
                    bool ok = (tg >= 0) && (tg < TDIM);
                    xhf = ok ? Xb[(size_t)(c0 + hc) * TDIM + tg] : 0.f;
                    if constexpr (MASKIN) mh = ok ? (mask + bb * TDIM)[tg] : 0.f;
                }
            }
        } else {
            const unsigned short* Xb = Xu + bb * Cin * TDIM;
            #pragma unroll
            for (int p = 0; p < 4; ++p)
                #pragma unroll
                for (int j = 0; j < 4; ++j)
                    xb[p][j] = Xb[(size_t)(c0 + cc0 + 16*p) * TDIM + t0 + cq + 16*j];
            if constexpr (KW == 3) {
                if (tid < 128) {
                    int tg = hcol ? t0 + 64 : t0 - 1;
                    bool ok = (tg >= 0) && (tg < TDIM);
                    xhb = ok ? Xb[(size_t)(c0 + hc) * TDIM + tg] : (unsigned short)0;
                }
            }
        }
    };
    auto writeX = [&]() {
        if constexpr (!INBF) {
            #pragma unroll
            for (int p = 0; p < 4; ++p)
                #pragma unroll
                for (int j = 0; j < 4; ++j) {
                    float v = xf[p][j];
                    if constexpr (MASKIN) v *= mf[j];
                    xs[H + cq + 16*j][cc0 + 16*p] = (unsigned short)f2bf(v);
                }
            if constexpr (KW == 3) {
                if (tid < 128) {
                    float v = xhf;
                    if constexpr (MASKIN) v *= mh;
                    xs[hcol ? ROWS - 1 : 0][hc] = (unsigned short)f2bf(v);
                }
            }
        } else {
            #pragma unroll
            for (int p = 0; p < 4; ++p)
                #pragma unroll
                for (int j = 0; j < 4; ++j)
                    xs[H + cq + 16*j][cc0 + 16*p] = xb[p][j];
            if constexpr (KW == 3) {
                if (tid < 128) xs[hcol ? ROWS - 1 : 0][hc] = xhb;
            }
        }
    };
    auto loadW = [&](int c0) {
        const unsigned short* Wc = Wb + c0;
        #pragma unroll
        for (int p = 0; p < KW * 4; ++p) {
            int idx = tid + p * 256;
            int k = idx >> 10;
            int rem = idx & 1023; int m = rem >> 4, c4 = rem & 15;
            wreg[p] = *(const uint2*)(Wc + ((size_t)k * M + m0 + m) * Cin + c4 * 4);
        }
    };
    auto writeW = [&]() {
        #pragma unroll
        for (int p = 0; p < KW * 4; ++p) {
            int idx = tid + p * 256;
            int k = idx >> 10;
            int rem = idx & 1023; int m = rem >> 4, c4 = rem & 15;
            *(uint2*)&wsm[k * 64 + m][c4 * 4] = wreg[p];
        }
    };

    loadX(0, 0);
    loadW(0);
    const int NC = Cin / CC;
    for (int ci = 0; ci < NC; ++ci) {
        int c0 = ci * CC;
        #pragma unroll
        for (int bi = 0; bi < NB; ++bi) {
            __syncthreads();                   // LDS consumers of prev step done
            writeX();
            if (bi == 0) writeW();
            bool lastStep = (ci == NC - 1) && (bi == NB - 1);
            if (!lastStep) {                   // issue next step's loads (T14)
                if (bi + 1 < NB) loadX(bi + 1, c0);
                else { loadX(0, c0 + CC); loadW(c0 + CC); }
            }
            __syncthreads();                   // LDS ready
            #pragma unroll
            for (int k = 0; k < KW; ++k) {
                #pragma unroll
                for (int ks = 0; ks < 2; ++ks) {
                    s16x8 a0 = *(const s16x8*)&xs[32*wr +  0 + lrow + k][ks*32 + lkg*8];
                    s16x8 a1 = *(const s16x8*)&xs[32*wr + 16 + lrow + k][ks*32 + lkg*8];
                    s16x8 b0 = *(const s16x8*)&wsm[k*64 + 32*wc +  0 + lrow][ks*32 + lkg*8];
                    s16x8 b1 = *(const s16x8*)&wsm[k*64 + 32*wc + 16 + lrow][ks*32 + lkg*8];
                    acc[bi][0][0] = __builtin_amdgcn_mfma_f32_16x16x32_bf16(a0, b0, acc[bi][0][0], 0, 0, 0);
                    acc[bi][0][1] = __builtin_amdgcn_mfma_f32_16x16x32_bf16(a0, b1, acc[bi][0][1], 0, 0, 0);
                    acc[bi][1][0] = __builtin_amdgcn_mfma_f32_16x16x32_bf16(a1, b0, acc[bi][1][0], 0, 0, 0);
                    acc[bi][1][1] = __builtin_amdgcn_mfma_f32_16x16x32_bf16(a1, b1, acc[bi][1][1], 0, 0, 0);
                }
            }
        }
    }

    // epilogue: per batch, bias/relu/mask -> LDS transpose -> coalesced store
    float* tile = (float*)smem_raw;            // [64][65]
    #pragma unroll
    for (int bi = 0; bi < NB; ++bi) {
        size_t bb = (size_t)(bz * NB + bi);
        const float* mbb = mask + bb * TDIM;
        __syncthreads();
        #pragma unroll
        for (int i = 0; i < 2; ++i) {
            #pragma unroll
            for (int j = 0; j < 2; ++j) {
                int ml = 32 * wc + 16 * j + lrow;
                float bv = bias[m0 + ml];
                #pragma unroll
                for (int r = 0; r < 4; ++r) {
                    int tl = 32 * wr + 16 * i + lkg * 4 + r;
                    float v = acc[bi][i][j][r] + bv;
                    if (RELU) v = fmaxf(v, 0.f);
                    if (OUTMASK) v *= mbb[t0 + tl];
                    tile[tl * 65 + ml] = v;
                }
            }
        }
        __syncthreads();
        for (int idx = tid; idx < 1024; idx += 256) {
            int m = idx >> 4, tq = (idx & 15) * 4;
            float o0 = tile[(tq + 0) * 65 + m];
            float o1 = tile[(tq + 1) * 65 + m];
            float o2 = tile[(tq + 2) * 65 + m];
            float o3 = tile[(tq + 3) * 65 + m];
            size_t off = (bb * M + m0 + m) * TDIM + t0 + tq;
            if constexpr (OUTBF) {
                uint2 u;
                u.x = f2bf(o0) | (f2bf(o1) << 16);
                u.y = f2bf(o2) | (f2bf(o3) << 16);
                *(uint2*)&Yu[off] = u;
            } else {
                *(float4*)&Yf[off] = make_float4(o0, o1, o2, o3);
            }
        }
    }
}

// ---------------------------------------------------------------------------
// MFMA flash attention (bf16 in / bf16 out).  64 q-rows/block, 4 waves.
// ---------------------------------------------------------------------------
__global__ __launch_bounds__(256) void attn_mfma(
    const unsigned short* __restrict__ qkv, const float* __restrict__ erk,
    const float* __restrict__ erv, unsigned short* __restrict__ out)
{
    constexpr int QP = 52;
    constexpr int KP = 52;
    constexpr int VP = 20;
    constexpr int PP = 36;

    __shared__ __align__(16) unsigned qs_lds[64 * QP];
    __shared__ __align__(16) unsigned ks_lds[32 * KP];
    __shared__ __align__(16) unsigned vt_lds[96 * VP];
    __shared__ __align__(16) unsigned p_lds[64 * PP];
    __shared__ float band_lds[64 * 20];
    __shared__ float lg_lds[64 * NR];
    __shared__ float ervs[NR * 96];
    __shared__ float rs_lds[64];
    __shared__ float statL[64], statA[64], statB[64];

    int bh = blockIdx.x;
    int b = bh >> 1, h = bh & 1;
    int t0 = blockIdx.y * 64;
    int tid = threadIdx.x;
    int w = tid >> 6, l = tid & 63;
    int lt = l & 15, g = l >> 4;
    int tblk = w * 16 + lt;
    int rowg = t0 + tblk;

    const unsigned short* qb = qkv + ((size_t)b * 576 + h * 96) * TDIM;
    const unsigned short* kb = qb + (size_t)192 * TDIM;
    const unsigned short* vb = qb + (size_t)384 * TDIM;

    for (int idx = tid; idx < 64 * 48; idx += 256) {
        int t = idx & 63, dp = idx >> 6;
        unsigned u0 = qb[(size_t)(2*dp) * TDIM + t0 + t];
        unsigned u1 = qb[(size_t)(2*dp + 1) * TDIM + t0 + t];
        qs_lds[t * QP + dp] = u0 | (u1 << 16);
    }
    for (int idx = tid; idx < NR * 96; idx += 256) ervs[idx] = erv[idx];
    for (int idx = tid; idx < 64 * 20; idx += 256) band_lds[idx] = 0.f;
    __syncthreads();

    for (int idx = tid; idx < 64 * NR; idx += 256) {
        int t = idx & 63, r = idx >> 6;
        const float* ek = erk + r * 96;
        float s = 0.f;
        #pragma unroll
        for (int dp = 0; dp < 48; ++dp) {
            unsigned u = qs_lds[t * QP + dp];
            s += bflo(u) * ek[2*dp] + bfhi(u) * ek[2*dp + 1];
        }
        lg_lds[t * NR + r] = s;
    }
    __syncthreads();

    s16x8 qf[3];
    #pragma unroll
    for (int j = 0; j < 3; ++j)
        qf[j] = *(const s16x8*)&qs_lds[tblk * QP + 16*j + 4*g];

    f32x4 o[6];
    #pragma unroll
    for (int dt = 0; dt < 6; ++dt) o[dt] = f32x4{0.f,0.f,0.f,0.f};
    float m_old = -1e30f, lsum_p = 0.f, A_p = 0.f, B_p = 0.f;

    unsigned short kr0[6], kr1[6];
    unsigned vr[6];
    int ksr[6], kdp[6], vdr[6], vsp[6];
    #pragma unroll
    for (int p = 0; p < 6; ++p) {
        int i2 = tid + p * 256;
        ksr[p] = i2 & 31; kdp[p] = i2 >> 5;
        vdr[p] = i2 >> 4; vsp[p] = i2 & 15;
    }
    #pragma unroll
    for (int p = 0; p < 6; ++p) {
        kr0[p] = kb[(size_t)(2*kdp[p]) * TDIM + ksr[p]];
        kr1[p] = kb[(size_t)(2*kdp[p] + 1) * TDIM + ksr[p]];
        vr[p]  = *(const unsigned*)(vb + (size_t)vdr[p] * TDIM + 2*vsp[p]);
    }

    for (int tile = 0; tile < 24; ++tile) {
        int s0 = tile * 32;
        __syncthreads();
        #pragma unroll
        for (int p = 0; p < 6; ++p) {
            ks_lds[ksr[p] * KP + kdp[p]] = (unsigned)kr0[p] | ((unsigned)kr1[p] << 16);
            vt_lds[vdr[p] * VP + vsp[p]] = vr[p];
        }
        if (tile < 23) {
            int sn = s0 + 32;
            #pragma unroll
            for (int p = 0; p < 6; ++p) {
                kr0[p] = kb[(size_t)(2*kdp[p]) * TDIM + sn + ksr[p]];
                kr1[p] = kb[(size_t)(2*kdp[p] + 1) * TDIM + sn + ksr[p]];
                vr[p]  = *(const unsigned*)(vb + (size_t)vdr[p] * TDIM + sn + 2*vsp[p]);
            }
        }
        __syncthreads();

        f32x4 st0 = f32x4{0.f,0.f,0.f,0.f}, st1 = f32x4{0.f,0.f,0.f,0.f};
        #pragma unroll
        for (int j = 0; j < 3; ++j) {
            s16x8 a0 = *(const s16x8*)&ks_lds[(     lt) * KP + 16*j + 4*g];
            s16x8 a1 = *(const s16x8*)&ks_lds[(16 + lt) * KP + 16*j + 4*g];
            st0 = __builtin_amdgcn_mfma_f32_16x16x32_bf16(a0, qf[j], st0, 0, 0, 0);
            st1 = __builtin_amdgcn_mfma_f32_16x16x32_bf16(a1, qf[j], st1, 0, 0, 0);
        }

        float p8[8];
        #pragma unroll
        for (int hh = 0; hh < 2; ++hh)
            #pragma unroll
            for (int r = 0; r < 4; ++r) {
                int sg = s0 + hh*16 + 4*g + r;
                int rel = min(max(rowg - sg + WREL, 0), 2*WREL);
                float sv = (hh == 0) ? st0[r] : st1[r];
                p8[hh*4 + r] = sv + lg_lds[tblk * NR + rel];
            }
        float mxn = m_old;
        #pragma unroll
        for (int i = 0; i < 8; ++i) mxn = fmaxf(mxn, p8[i]);
        mxn = fmaxf(mxn, __shfl_xor(mxn, 16));
        mxn = fmaxf(mxn, __shfl_xor(mxn, 32));
        float rs = __expf(m_old - mxn);
        m_old = mxn;
        if (g == 0) rs_lds[tblk] = rs;
        if (__any(rs != 1.0f)) {
            for (int i = l; i < 16 * 19; i += 64) {
                int tt = i / 19, rr = i % 19;
                band_lds[(w*16 + tt) * 20 + rr] *= rs_lds[w*16 + tt];
            }
            lsum_p *= rs; A_p *= rs; B_p *= rs;
            float rsg[4];
            #pragma unroll
            for (int r = 0; r < 4; ++r) rsg[r] = rs_lds[w*16 + 4*g + r];
            #pragma unroll
            for (int dt = 0; dt < 6; ++dt)
                #pragma unroll
                for (int r = 0; r < 4; ++r) o[dt][r] *= rsg[r];
        }

        float e8[8];
        #pragma unroll
        for (int hh = 0; hh < 2; ++hh)
            #pragma unroll
            for (int r = 0; r < 4; ++r) {
                int i = hh*4 + r;
                float e = __expf(p8[i] - mxn);
                e8[i] = e;
                lsum_p += e;
                int grel = rowg - (s0 + hh*16 + 4*g + r) + WREL;
                if (grel <= 0) A_p += e;
                else if (grel >= 2*WREL) B_p += e;
                else band_lds[tblk * 20 + grel - 1] = e;
            }

        #pragma unroll
        for (int hh = 0; hh < 2; ++hh)
            #pragma unroll
            for (int r2 = 0; r2 < 2; ++r2) {
                float e0 = e8[hh*4 + 2*r2], e1 = e8[hh*4 + 2*r2 + 1];
                unsigned h0 = f2bf(e0), h1 = f2bf(e1);
                float lo0 = e0 - bflo(h0);
                float lo1 = e1 - bflo(h1);
                int s2 = hh*8 + g*2 + r2;
                p_lds[tblk * PP + s2]      = h0 | (h1 << 16);
                p_lds[tblk * PP + 16 + s2] = f2bf(lo0) | (f2bf(lo1) << 16);
            }

        s16x8 pa_h = *(const s16x8*)&p_lds[tblk * PP + 4*g];
        s16x8 pa_l = *(const s16x8*)&p_lds[tblk * PP + 16 + 4*g];
        #pragma unroll
        for (int dt = 0; dt < 6; ++dt) {
            s16x8 vf = *(const s16x8*)&vt_lds[(16*dt + lt) * VP + 4*g];
            o[dt] = __builtin_amdgcn_mfma_f32_16x16x32_bf16(pa_h, vf, o[dt], 0, 0, 0);
            o[dt] = __builtin_amdgcn_mfma_f32_16x16x32_bf16(pa_l, vf, o[dt], 0, 0, 0);
        }
    }

    lsum_p += __shfl_xor(lsum_p, 16); lsum_p += __shfl_xor(lsum_p, 32);
    A_p    += __shfl_xor(A_p, 16);    A_p    += __shfl_xor(A_p, 32);
    B_p    += __shfl_xor(B_p, 16);    B_p    += __shfl_xor(B_p, 32);
    if (g == 0) { statL[tblk] = lsum_p; statA[tblk] = A_p; statB[tblk] = B_p; }

    unsigned short* ob = out + ((size_t)b * CDIM + h * 96) * TDIM;
    #pragma unroll
    for (int r = 0; r < 4; ++r) {
        int tt = w*16 + 4*g + r;
        float Ls = statL[tt], Av = statA[tt], Bv = statB[tt];
        float inv = 1.0f / Ls;
        float bnd[19];
        #pragma unroll
        for (int rel = 1; rel <= 19; ++rel) bnd[rel-1] = band_lds[tt * 20 + rel - 1];
        #pragma unroll
        for (int dt = 0; dt < 6; ++dt) {
            int d = 16*dt + lt;
            float val = o[dt][r] + Av * ervs[d] + Bv * ervs[2*WREL*96 + d];
            #pragma unroll
            for (int rel = 1; rel <= 19; ++rel)
                val += bnd[rel-1] * ervs[rel*96 + d];
            o[dt][r] = val * inv;
        }
    }
    #pragma unroll
    for (int dt = 0; dt < 6; ++dt) {
        int d = 16*dt + lt;
        uint2 u;
        u.x = f2bf(o[dt][0]) | (f2bf(o[dt][1]) << 16);
        u.y = f2bf(o[dt][2]) | (f2bf(o[dt][3]) << 16);
        *(uint2*)&ob[(size_t)d * TDIM + t0 + w*16 + 4*g] = u;
    }
}

// ---------------------------------------------------------------------------
// Residual + channel LayerNorm (f32).
// ---------------------------------------------------------------------------
__global__ __launch_bounds__(256) void ln_kernel(
    const float* __restrict__ xres, const float* __restrict__ y,
    const float* __restrict__ gamma, const float* __restrict__ beta,
    const float* __restrict__ mask, float* __restrict__ outp, int applymask)
{
    int b = blockIdx.y;
    int tl = threadIdx.x & 31;
    int g  = threadIdx.x >> 5;
    int t  = blockIdx.x * 32 + tl;
    int cb = g * 24;

    __shared__ float part[2][8][32];

    const float* xb = xres + (size_t)b * CDIM * TDIM + t;
    const float* yb = y    + (size_t)b * CDIM * TDIM + t;

    float vv[24];
    float s = 0.f, ss = 0.f;
    #pragma unroll
    for (int c = 0; c < 24; ++c) {
        float v = xb[(size_t)(cb + c) * TDIM] + yb[(size_t)(cb + c) * TDIM];
        vv[c] = v; s += v; ss += v * v;
    }
    part[0][g][tl] = s;
    part[1][g][tl] = ss;
    __syncthreads();
    float S = 0.f, SS = 0.f;
    #pragma unroll
    for (int gg = 0; gg < 8; ++gg) { S += part[0][gg][tl]; SS += part[1][gg][tl]; }
    float mean = S * (1.0f / 192.0f);
    float var  = SS * (1.0f / 192.0f) - mean * mean;
    float rstd = rsqrtf(var + 1e-5f);
    float mk = applymask ? mask[(size_t)b * TDIM + t] : 1.f;

    float* ob = outp + (size_t)b * CDIM * TDIM + t;
    #pragma unroll
    for (int c = 0; c < 24; ++c) {
        float rr = gamma[cb + c] * ((vv[c] - mean) * rstd) + beta[cb + c];
        if (applymask) rr *= mk;
        ob[(size_t)(cb + c) * TDIM] = rr;
    }
}

// ---------------------------------------------------------------------------
extern "C" void kernel_launch(void* const* d_in, const int* in_sizes, int n_in,
                              void* d_out, int out_size, void* d_ws, size_t ws_size,
                              hipStream_t stream)
{
    const float* x_in  = (const float*)d_in[0];
    const float* mask  = (const float*)d_in[1];
    const float* w_q   = (const float*)d_in[2];
    const float* b_q   = (const float*)d_in[3];
    const float* w_k   = (const float*)d_in[4];
    const float* b_k   = (const float*)d_in[5];
    const float* w_v   = (const float*)d_in[6];
    const float* b_v   = (const float*)d_in[7];
    const float* w_o   = (const float*)d_in[8];
    const float* b_o   = (const float*)d_in[9];
    const float* erk   = (const float*)d_in[10];
    const float* erv   = (const float*)d_in[11];
    const float* g1    = (const float*)d_in[12];
    const float* be1   = (const float*)d_in[13];
    const float* w_f1  = (const float*)d_in[14];
    const float* b_f1  = (const float*)d_in[15];
    const float* w_f2  = (const float*)d_in[16];
    const float* b_f2  = (const float*)d_in[17];
    const float* g2    = (const float*)d_in[18];
    const float* be2   = (const float*)d_in[19];

    char* wsb = (char*)d_ws;
    float* out = (float*)d_out;

    const unsigned short* WBQKV = (const unsigned short*)(wsb + OFFB_WQKV);
    const unsigned short* WBO   = (const unsigned short*)(wsb + OFFB_WO);
    const unsigned short* WBF1  = (const unsigned short*)(wsb + OFFB_WF1);
    const unsigned short* WBF2  = (const unsigned short*)(wsb + OFFB_WF2);
    const float*  BQKV  = (const float*)(wsb + OFFB_BQKV);
    unsigned short* QKVB = (unsigned short*)(wsb + OFFB_SHARED);
    unsigned short* ATTN = (unsigned short*)(wsb + OFFB_SHARED + SZB_QKV);
    unsigned short* H1   = (unsigned short*)(wsb + OFFB_SHARED);  // aliases (dead)
    float* YB   = (float*)(wsb + OFFB_Y);
    float* XCUR = (float*)(wsb + OFFB_XCUR);

    prep_kernel<<<dim3(1024, 5), 256, 0, stream>>>(w_q, w_k, w_v, w_o, w_f1, w_f2,
                                                   b_q, b_k, b_v, wsb);

    for (int l = 0; l < LNUM; ++l) {
        const float* xc = (l == 0) ? x_in : XCUR;

        // QKV: f32 in (masked), bf16 out, NB=2
        gemm_mfma<1, false, true, false, false, true, 2><<<dim3(12, 9, 4), 256, 0, stream>>>(
            WBQKV + (size_t)l * 576 * 192, xc, BQKV + l * 576, mask, QKVB, 576, 192);

        attn_mfma<<<dim3(16, 12), 256, 0, stream>>>(
            QKVB, erk + (size_t)l * NR * KCD, erv + (size_t)l * NR * KCD, ATTN);

        // O: bf16 in, f32 out
        gemm_mfma<1, true, false, false, false, false, 1><<<dim3(12, 3, 8), 256, 0, stream>>>(
            WBO + (size_t)l * 192 * 192, ATTN, b_o + l * 192, mask, YB, 192, 192);

        ln_kernel<<<dim3(24, 8), 256, 0, stream>>>(xc, YB, g1 + l * 192, be1 + l * 192,
                                                   mask, XCUR, 0);

        // F1: f32 in (masked), relu, OUT masked (pre-mask H1), bf16 out, NB=2
        gemm_mfma<3, false, true, true, true, true, 2><<<dim3(12, 12, 4), 256, 0, stream>>>(
            WBF1 + (size_t)l * 3 * 768 * 192, XCUR, b_f1 + l * FCH, mask, H1, 768, 192);

        // F2: bf16 in (pre-masked), f32 out masked
        gemm_mfma<3, true, false, false, true, false, 1><<<dim3(12, 3, 8), 256, 0, stream>>>(
            WBF2 + (size_t)l * 3 * 192 * 768, H1, b_f2 + l * 192, mask, YB, 192, 768);

        bool last = (l == LNUM - 1);
        ln_kernel<<<dim3(24, 8), 256, 0, stream>>>(XCUR, YB, g2 + l * 192, be2 + l * 192,
                                                   mask, last ? out : XCUR, last ? 1 : 0);
    }
}